// Round 1
// baseline (8783.381 us; speedup 1.0000x reference)
//
#include <hip/hip_runtime.h>
#include <utility>

// ---------------------------------------------------------------------------
// fp32 GEMM: out[N,128] = act(A[N,128] @ W[128,128] + bias[128])
// Block 256 threads, tile = 64 rows x 128 cols. A-tile staged in LDS (32 KB),
// W streamed from global (64 KB, L1/L2-hot since every block rereads it).
// Thread micro-tile: 8 rows x 4 cols (acc[8][4]); cg = tid&31 -> cols 4cg..4cg+3,
// rg = tid>>5 -> rows rg*8..rg*8+7.
// ---------------------------------------------------------------------------
__global__ __launch_bounds__(256) void gemm_128(
    const float* __restrict__ A, const float* __restrict__ W,
    const float* __restrict__ bias, float* __restrict__ out,
    int N, int relu)
{
    __shared__ float As[64][128];
    const int tid = threadIdx.x;
    const int cg = tid & 31;
    const int rg = tid >> 5;

    for (int tile = blockIdx.x; tile * 64 < N; tile += gridDim.x) {
        const int row0 = tile * 64;
        const int rows = min(64, N - row0);

        // stage A tile: rows*32 float4s, coalesced
        for (int i = tid; i < rows * 32; i += 256) {
            int r = i >> 5, c4 = i & 31;
            ((float4*)As[r])[c4] = ((const float4*)(A + (size_t)(row0 + r) * 128))[c4];
        }
        __syncthreads();

        float acc[8][4];
        const float4 bv = ((const float4*)bias)[cg];
        #pragma unroll
        for (int r = 0; r < 8; r++) {
            acc[r][0] = bv.x; acc[r][1] = bv.y; acc[r][2] = bv.z; acc[r][3] = bv.w;
        }

        for (int k = 0; k < 128; k += 4) {
            const float4 w0 = ((const float4*)(W + (size_t)(k + 0) * 128))[cg];
            const float4 w1 = ((const float4*)(W + (size_t)(k + 1) * 128))[cg];
            const float4 w2 = ((const float4*)(W + (size_t)(k + 2) * 128))[cg];
            const float4 w3 = ((const float4*)(W + (size_t)(k + 3) * 128))[cg];
            #pragma unroll
            for (int r = 0; r < 8; r++) {
                const float4 a4 = *(const float4*)&As[rg * 8 + r][k];
                acc[r][0] += a4.x * w0.x; acc[r][1] += a4.x * w0.y;
                acc[r][2] += a4.x * w0.z; acc[r][3] += a4.x * w0.w;
                acc[r][0] += a4.y * w1.x; acc[r][1] += a4.y * w1.y;
                acc[r][2] += a4.y * w1.z; acc[r][3] += a4.y * w1.w;
                acc[r][0] += a4.z * w2.x; acc[r][1] += a4.z * w2.y;
                acc[r][2] += a4.z * w2.z; acc[r][3] += a4.z * w2.w;
                acc[r][0] += a4.w * w3.x; acc[r][1] += a4.w * w3.y;
                acc[r][2] += a4.w * w3.z; acc[r][3] += a4.w * w3.w;
            }
        }

        #pragma unroll
        for (int r = 0; r < 8; r++) {
            const int row = row0 + rg * 8 + r;
            if (row < N) {
                float4 v = make_float4(acc[r][0], acc[r][1], acc[r][2], acc[r][3]);
                if (relu) {
                    v.x = fmaxf(v.x, 0.f); v.y = fmaxf(v.y, 0.f);
                    v.z = fmaxf(v.z, 0.f); v.w = fmaxf(v.w, 0.f);
                }
                ((float4*)(out + (size_t)row * 128))[cg] = v;
            }
        }
        __syncthreads();  // protect As before next tile's stage
    }
}

// ---------------------------------------------------------------------------
// Scatter-add: out[dst[e]] += h[src[e]] over E edges, D=128.
// Thread handles (edge, 4-float chunk): 32 threads per edge, float4 gather,
// 4 fp32 atomics each. out must be pre-initialized with h (z = h + agg).
// ---------------------------------------------------------------------------
__global__ __launch_bounds__(256) void scatter_add(
    const float* __restrict__ h, const int* __restrict__ src,
    const int* __restrict__ dst, float* __restrict__ out, int E)
{
    const int stride = gridDim.x * blockDim.x;
    const long long total = (long long)E * 32;
    for (long long i = (long long)blockIdx.x * blockDim.x + threadIdx.x; i < total; i += stride) {
        const int e = (int)(i >> 5);
        const int l = (int)(i & 31);
        const int s = src[e];
        const int d = dst[e];
        const float4 v = ((const float4*)(h + (size_t)s * 128))[l];
        float* o = out + (size_t)d * 128 + l * 4;
        atomicAdd(o + 0, v.x);
        atomicAdd(o + 1, v.y);
        atomicAdd(o + 2, v.z);
        atomicAdd(o + 3, v.w);
    }
}

// ---------------------------------------------------------------------------
// BN batch stats: stats[c] = sum over rows, stats[128+c] = sumsq. Pre-zeroed.
// ---------------------------------------------------------------------------
__global__ __launch_bounds__(256) void bn_stats(
    const float* __restrict__ z, float* __restrict__ stats, int N)
{
    const int c = threadIdx.x & 127;
    const int half = threadIdx.x >> 7;  // 0..1
    float s = 0.f, ss = 0.f;
    for (int r = blockIdx.x * 2 + half; r < N; r += gridDim.x * 2) {
        const float v = z[(size_t)r * 128 + c];
        s += v; ss += v * v;
    }
    __shared__ float red[256];
    red[threadIdx.x] = s;
    __syncthreads();
    if (half == 0) atomicAdd(&stats[c], s + red[128 + c]);
    __syncthreads();
    red[threadIdx.x] = ss;
    __syncthreads();
    if (half == 0) atomicAdd(&stats[128 + c], ss + red[128 + c]);
}

// ---------------------------------------------------------------------------
// BN apply (training-mode batch stats, biased var) + ReLU, in-place.
// ---------------------------------------------------------------------------
__global__ __launch_bounds__(256) void bn_apply_relu(
    float* __restrict__ z, const float* __restrict__ stats,
    const float* __restrict__ gamma, const float* __restrict__ beta,
    int N, float invN)
{
    const long long total = (long long)N * 32;  // float4 count
    const int stride = gridDim.x * blockDim.x;
    for (long long i = (long long)blockIdx.x * blockDim.x + threadIdx.x; i < total; i += stride) {
        const int c4 = (int)(i & 31);
        const float4 S  = ((const float4*)stats)[c4];
        const float4 SS = ((const float4*)(stats + 128))[c4];
        const float4 g = ((const float4*)gamma)[c4];
        const float4 b = ((const float4*)beta)[c4];
        float4 mu, sc;
        mu.x = S.x * invN; mu.y = S.y * invN; mu.z = S.z * invN; mu.w = S.w * invN;
        sc.x = rsqrtf(fmaxf(SS.x * invN - mu.x * mu.x, 0.f) + 1e-5f) * g.x;
        sc.y = rsqrtf(fmaxf(SS.y * invN - mu.y * mu.y, 0.f) + 1e-5f) * g.y;
        sc.z = rsqrtf(fmaxf(SS.z * invN - mu.z * mu.z, 0.f) + 1e-5f) * g.z;
        sc.w = rsqrtf(fmaxf(SS.w * invN - mu.w * mu.w, 0.f) + 1e-5f) * g.w;
        float4 v = ((float4*)z)[i];
        v.x = fmaxf((v.x - mu.x) * sc.x + b.x, 0.f);
        v.y = fmaxf((v.y - mu.y) * sc.y + b.y, 0.f);
        v.z = fmaxf((v.z - mu.z) * sc.z + b.z, 0.f);
        v.w = fmaxf((v.w - mu.w) * sc.w + b.w, 0.f);
        ((float4*)z)[i] = v;
    }
}

// ---------------------------------------------------------------------------
// Classifier: out[e] = dot(h[ia[e]], h[ib[e]]), D=128.
// 32 lanes per edge, float4 per lane, shuffle reduction within the 32-group.
// ---------------------------------------------------------------------------
__global__ __launch_bounds__(256) void edge_dot(
    const float* __restrict__ h, const int* __restrict__ ia,
    const int* __restrict__ ib, float* __restrict__ out, int EL)
{
    const int stride = gridDim.x * blockDim.x;
    const long long total = (long long)EL * 32;
    for (long long i = (long long)blockIdx.x * blockDim.x + threadIdx.x; i < total; i += stride) {
        const int e = (int)(i >> 5);
        const int l = (int)(i & 31);
        const int a = ia[e];
        const int b = ib[e];
        const float4 va = ((const float4*)(h + (size_t)a * 128))[l];
        const float4 vb = ((const float4*)(h + (size_t)b * 128))[l];
        float d = va.x * vb.x + va.y * vb.y + va.z * vb.z + va.w * vb.w;
        #pragma unroll
        for (int off = 16; off > 0; off >>= 1) d += __shfl_xor(d, off);
        if (l == 0) out[e] = d;
    }
}

extern "C" void kernel_launch(void* const* d_in, const int* in_sizes, int n_in,
                              void* d_out, int out_size, void* d_ws, size_t ws_size,
                              hipStream_t stream)
{
    const float* x     = (const float*)d_in[0];
    const float* lin_w = (const float*)d_in[1];
    const float* lin_b = (const float*)d_in[2];
    const float* W1    = (const float*)d_in[3];
    const float* b1    = (const float*)d_in[4];
    const float* gamma = (const float*)d_in[5];
    const float* beta  = (const float*)d_in[6];
    const float* W2    = (const float*)d_in[7];
    const float* b2    = (const float*)d_in[8];
    const int*   ei    = (const int*)d_in[9];
    const int*   eli   = (const int*)d_in[10];
    float* out = (float*)d_out;

    const int N  = in_sizes[0] / 128;
    const int E  = in_sizes[9] / 2;
    const int EL = in_sizes[10] / 2;
    const size_t nd = (size_t)N * 128;

    float* A     = (float*)d_ws;       // h
    float* B     = A + nd;             // z_pre / next h
    float* C     = B + nd;             // gemm out / normalized
    float* stats = C + nd;             // 256 floats

    const int gemm_grid = (N + 63) / 64;
    const float invN = 1.0f / (float)N;

    // h = x @ lin_w + lin_b
    gemm_128<<<gemm_grid, 256, 0, stream>>>(x, lin_w, lin_b, A, N, 0);

    for (int l = 0; l < 3; l++) {
        // z_pre = h + segment_sum(h[src], dst)
        hipMemcpyAsync(B, A, nd * sizeof(float), hipMemcpyDeviceToDevice, stream);
        scatter_add<<<8192, 256, 0, stream>>>(A, ei, ei + E, B, E);
        // z = z_pre @ W1[l] + b1[l]
        gemm_128<<<gemm_grid, 256, 0, stream>>>(B, W1 + (size_t)l * 128 * 128,
                                                b1 + (size_t)l * 128, C, N, 0);
        // batch-norm (training stats) + relu
        hipMemsetAsync(stats, 0, 256 * sizeof(float), stream);
        bn_stats<<<1024, 256, 0, stream>>>(C, stats, N);
        bn_apply_relu<<<4096, 256, 0, stream>>>(C, stats, gamma + (size_t)l * 128,
                                                beta + (size_t)l * 128, N, invN);
        // h = relu(z @ W2[l] + b2[l])
        gemm_128<<<gemm_grid, 256, 0, stream>>>(C, W2 + (size_t)l * 128 * 128,
                                                b2 + (size_t)l * 128, B, N, 1);
        std::swap(A, B);
    }

    // pred = rowwise dot of endpoint embeddings
    edge_dot<<<8192, 256, 0, stream>>>(A, eli, eli + EL, out, EL);
}

// Round 2
// 1282.988 us; speedup vs baseline: 6.8460x; 6.8460x over previous
//
#include <hip/hip_runtime.h>

// ===========================================================================
// Pipeline: h = x@lin_w+b; 3× [gather-agg -> gemm1 -> BN+relu -> gemm2+relu];
// edge_dot. Aggregation via CSR (built once per call) instead of atomics:
// R0 showed scatter_add wrote 3.28 GB/dispatch to HBM (64B line flush per
// 16B atomic group) = 2.68 ms x3. CSR gather reads h rows (51.2 MB, L3-
// resident) and writes each output row exactly once.
// ===========================================================================

// ---------------------------------------------------------------------------
// fp32 GEMM: out[N,128] = act(A[N,128] @ W[128,128] + bias[128])
// In-place safe (out==A): each block stages its 64 rows to LDS before any
// write, and no other block reads those rows.
// ---------------------------------------------------------------------------
__global__ __launch_bounds__(256) void gemm_128(
    const float* __restrict__ A, const float* __restrict__ W,
    const float* __restrict__ bias, float* __restrict__ out,
    int N, int relu)
{
    __shared__ float As[64][128];
    const int tid = threadIdx.x;
    const int cg = tid & 31;
    const int rg = tid >> 5;

    const int tile = blockIdx.x;
    const int row0 = tile * 64;
    if (row0 >= N) return;
    const int rows = min(64, N - row0);

    for (int i = tid; i < rows * 32; i += 256) {
        int r = i >> 5, c4 = i & 31;
        ((float4*)As[r])[c4] = ((const float4*)(A + (size_t)(row0 + r) * 128))[c4];
    }
    __syncthreads();

    float acc[8][4];
    const float4 bv = ((const float4*)bias)[cg];
    #pragma unroll
    for (int r = 0; r < 8; r++) {
        acc[r][0] = bv.x; acc[r][1] = bv.y; acc[r][2] = bv.z; acc[r][3] = bv.w;
    }

    for (int k = 0; k < 128; k += 4) {
        const float4 w0 = ((const float4*)(W + (size_t)(k + 0) * 128))[cg];
        const float4 w1 = ((const float4*)(W + (size_t)(k + 1) * 128))[cg];
        const float4 w2 = ((const float4*)(W + (size_t)(k + 2) * 128))[cg];
        const float4 w3 = ((const float4*)(W + (size_t)(k + 3) * 128))[cg];
        #pragma unroll
        for (int r = 0; r < 8; r++) {
            const float4 a4 = *(const float4*)&As[rg * 8 + r][k];
            acc[r][0] += a4.x * w0.x; acc[r][1] += a4.x * w0.y;
            acc[r][2] += a4.x * w0.z; acc[r][3] += a4.x * w0.w;
            acc[r][0] += a4.y * w1.x; acc[r][1] += a4.y * w1.y;
            acc[r][2] += a4.y * w1.z; acc[r][3] += a4.y * w1.w;
            acc[r][0] += a4.z * w2.x; acc[r][1] += a4.z * w2.y;
            acc[r][2] += a4.z * w2.z; acc[r][3] += a4.z * w2.w;
            acc[r][0] += a4.w * w3.x; acc[r][1] += a4.w * w3.y;
            acc[r][2] += a4.w * w3.z; acc[r][3] += a4.w * w3.w;
        }
    }

    #pragma unroll
    for (int r = 0; r < 8; r++) {
        const int row = row0 + rg * 8 + r;
        if (row < N) {
            float4 v = make_float4(acc[r][0], acc[r][1], acc[r][2], acc[r][3]);
            if (relu) {
                v.x = fmaxf(v.x, 0.f); v.y = fmaxf(v.y, 0.f);
                v.z = fmaxf(v.z, 0.f); v.w = fmaxf(v.w, 0.f);
            }
            ((float4*)(out + (size_t)row * 128))[cg] = v;
        }
    }
}

// ---------------------------------------------------------------------------
// CSR build step 1: degree histogram over dst.
// ---------------------------------------------------------------------------
__global__ __launch_bounds__(256) void hist_deg(
    const int* __restrict__ dst, int* __restrict__ deg, int E)
{
    const int stride = gridDim.x * blockDim.x;
    for (int e = blockIdx.x * blockDim.x + threadIdx.x; e < E; e += stride)
        atomicAdd(&deg[dst[e]], 1);
}

// ---------------------------------------------------------------------------
// CSR build step 2: 3-phase exclusive scan. Phase A: per-1024-chunk local
// exclusive scan into rowptr + chunk total into bsum. Phase B: 1-thread
// exclusive scan of bsum (~N/1024 entries). Chunk base (bsum[node>>10]) is
// added on the fly by consumers — no phase C pass.
// ---------------------------------------------------------------------------
__global__ __launch_bounds__(256) void scan_local(
    const int* __restrict__ deg, int* __restrict__ rowptr,
    int* __restrict__ bsum, int N)
{
    __shared__ int sh[256];
    const int t = threadIdx.x;
    const int base = blockIdx.x * 1024 + t * 4;
    int v[4], s = 0;
    #pragma unroll
    for (int k = 0; k < 4; k++) {
        v[k] = (base + k < N) ? deg[base + k] : 0;
        s += v[k];
    }
    sh[t] = s;
    __syncthreads();
    for (int off = 1; off < 256; off <<= 1) {
        int x = (t >= off) ? sh[t - off] : 0;
        __syncthreads();
        sh[t] += x;
        __syncthreads();
    }
    int run = sh[t] - s;  // exclusive prefix for this thread's 4 elements
    #pragma unroll
    for (int k = 0; k < 4; k++) {
        if (base + k < N) rowptr[base + k] = run;
        run += v[k];
    }
    if (t == 255) bsum[blockIdx.x] = sh[255];
}

__global__ void scan_bsum(int* __restrict__ bsum, int nb)
{
    if (threadIdx.x == 0 && blockIdx.x == 0) {
        int acc = 0;
        for (int i = 0; i < nb; i++) {
            int t = bsum[i];
            bsum[i] = acc;
            acc += t;
        }
    }
}

// ---------------------------------------------------------------------------
// CSR build step 3: scatter src ids into col[] via per-node cursors.
// ---------------------------------------------------------------------------
__global__ __launch_bounds__(256) void fill_col(
    const int* __restrict__ src, const int* __restrict__ dst,
    const int* __restrict__ rowptr, const int* __restrict__ bsum,
    int* __restrict__ cur, int* __restrict__ col, int E)
{
    const int stride = gridDim.x * blockDim.x;
    for (int e = blockIdx.x * blockDim.x + threadIdx.x; e < E; e += stride) {
        const int d = dst[e];
        const int p = atomicAdd(&cur[d], 1);
        col[rowptr[d] + bsum[d >> 10] + p] = src[e];
    }
}

// ---------------------------------------------------------------------------
// Fused aggregation: out[i] = h[i] + sum_{j in CSR(i)} h[col[j]].
// 32 lanes per node, float4 per lane (512 B contiguous per row read).
// ---------------------------------------------------------------------------
__global__ __launch_bounds__(256) void gather_agg(
    const float* __restrict__ h, const int* __restrict__ rowptr,
    const int* __restrict__ bsum, const int* __restrict__ deg,
    const int* __restrict__ col, float* __restrict__ out, int N)
{
    const long long total = (long long)N * 32;
    const int stride = gridDim.x * blockDim.x;
    for (long long i = (long long)blockIdx.x * blockDim.x + threadIdx.x; i < total; i += stride) {
        const int node = (int)(i >> 5);
        const int lane = (int)(i & 31);
        const int start = rowptr[node] + bsum[node >> 10];
        const int cnt = deg[node];
        float4 v = ((const float4*)(h + (size_t)node * 128))[lane];
        for (int j = 0; j < cnt; j++) {
            const int c = col[start + j];
            const float4 u = ((const float4*)(h + (size_t)c * 128))[lane];
            v.x += u.x; v.y += u.y; v.z += u.z; v.w += u.w;
        }
        ((float4*)(out + (size_t)node * 128))[lane] = v;
    }
}

// ---------------------------------------------------------------------------
// BN batch stats: stats[c] = sum, stats[128+c] = sumsq. Pre-zeroed.
// ---------------------------------------------------------------------------
__global__ __launch_bounds__(256) void bn_stats(
    const float* __restrict__ z, float* __restrict__ stats, int N)
{
    const int c = threadIdx.x & 127;
    const int half = threadIdx.x >> 7;
    float s = 0.f, ss = 0.f;
    for (int r = blockIdx.x * 2 + half; r < N; r += gridDim.x * 2) {
        const float v = z[(size_t)r * 128 + c];
        s += v; ss += v * v;
    }
    __shared__ float red[256];
    red[threadIdx.x] = s;
    __syncthreads();
    if (half == 0) atomicAdd(&stats[c], s + red[128 + c]);
    __syncthreads();
    red[threadIdx.x] = ss;
    __syncthreads();
    if (half == 0) atomicAdd(&stats[128 + c], ss + red[128 + c]);
}

// ---------------------------------------------------------------------------
// BN apply (batch stats, biased var) + ReLU, in-place.
// ---------------------------------------------------------------------------
__global__ __launch_bounds__(256) void bn_apply_relu(
    float* __restrict__ z, const float* __restrict__ stats,
    const float* __restrict__ gamma, const float* __restrict__ beta,
    int N, float invN)
{
    const long long total = (long long)N * 32;
    const int stride = gridDim.x * blockDim.x;
    for (long long i = (long long)blockIdx.x * blockDim.x + threadIdx.x; i < total; i += stride) {
        const int c4 = (int)(i & 31);
        const float4 S  = ((const float4*)stats)[c4];
        const float4 SS = ((const float4*)(stats + 128))[c4];
        const float4 g = ((const float4*)gamma)[c4];
        const float4 b = ((const float4*)beta)[c4];
        float4 mu, sc;
        mu.x = S.x * invN; mu.y = S.y * invN; mu.z = S.z * invN; mu.w = S.w * invN;
        sc.x = rsqrtf(fmaxf(SS.x * invN - mu.x * mu.x, 0.f) + 1e-5f) * g.x;
        sc.y = rsqrtf(fmaxf(SS.y * invN - mu.y * mu.y, 0.f) + 1e-5f) * g.y;
        sc.z = rsqrtf(fmaxf(SS.z * invN - mu.z * mu.z, 0.f) + 1e-5f) * g.z;
        sc.w = rsqrtf(fmaxf(SS.w * invN - mu.w * mu.w, 0.f) + 1e-5f) * g.w;
        float4 v = ((float4*)z)[i];
        v.x = fmaxf((v.x - mu.x) * sc.x + b.x, 0.f);
        v.y = fmaxf((v.y - mu.y) * sc.y + b.y, 0.f);
        v.z = fmaxf((v.z - mu.z) * sc.z + b.z, 0.f);
        v.w = fmaxf((v.w - mu.w) * sc.w + b.w, 0.f);
        ((float4*)z)[i] = v;
    }
}

// ---------------------------------------------------------------------------
// Classifier: out[e] = dot(h[ia[e]], h[ib[e]]).
// ---------------------------------------------------------------------------
__global__ __launch_bounds__(256) void edge_dot(
    const float* __restrict__ h, const int* __restrict__ ia,
    const int* __restrict__ ib, float* __restrict__ out, int EL)
{
    const int stride = gridDim.x * blockDim.x;
    const long long total = (long long)EL * 32;
    for (long long i = (long long)blockIdx.x * blockDim.x + threadIdx.x; i < total; i += stride) {
        const int e = (int)(i >> 5);
        const int l = (int)(i & 31);
        const int a = ia[e];
        const int b = ib[e];
        const float4 va = ((const float4*)(h + (size_t)a * 128))[l];
        const float4 vb = ((const float4*)(h + (size_t)b * 128))[l];
        float d = va.x * vb.x + va.y * vb.y + va.z * vb.z + va.w * vb.w;
        #pragma unroll
        for (int off = 16; off > 0; off >>= 1) d += __shfl_xor(d, off);
        if (l == 0) out[e] = d;
    }
}

extern "C" void kernel_launch(void* const* d_in, const int* in_sizes, int n_in,
                              void* d_out, int out_size, void* d_ws, size_t ws_size,
                              hipStream_t stream)
{
    const float* x     = (const float*)d_in[0];
    const float* lin_w = (const float*)d_in[1];
    const float* lin_b = (const float*)d_in[2];
    const float* W1    = (const float*)d_in[3];
    const float* b1    = (const float*)d_in[4];
    const float* gamma = (const float*)d_in[5];
    const float* beta  = (const float*)d_in[6];
    const float* W2    = (const float*)d_in[7];
    const float* b2    = (const float*)d_in[8];
    const int*   ei    = (const int*)d_in[9];
    const int*   eli   = (const int*)d_in[10];
    float* out = (float*)d_out;

    const int N  = in_sizes[0] / 128;
    const int E  = in_sizes[9] / 2;
    const int EL = in_sizes[10] / 2;
    const size_t nd = (size_t)N * 128;
    const int nb = (N + 1023) / 1024;  // scan chunks

    // ws layout: A[nd] | B[nd] | deg[N] | rowptr[N] | cur[N] | bsum[nb] | col[E] | stats[256]
    float* A      = (float*)d_ws;
    float* B      = A + nd;
    int*   deg    = (int*)(B + nd);
    int*   rowptr = deg + N;
    int*   cur    = rowptr + N;
    int*   bsum   = cur + N;
    int*   col    = bsum + nb;
    float* stats  = (float*)(col + E);

    const int gemm_grid = (N + 63) / 64;
    const float invN = 1.0f / (float)N;

    // ---- CSR build (graph is identical for all 3 layers) ----
    hipMemsetAsync(deg, 0, (size_t)2 * N * sizeof(int), stream);  // deg + rowptr... deg & cur
    hipMemsetAsync(cur, 0, (size_t)N * sizeof(int), stream);
    hist_deg<<<4096, 256, 0, stream>>>(ei + E, deg, E);
    scan_local<<<nb, 256, 0, stream>>>(deg, rowptr, bsum, N);
    scan_bsum<<<1, 64, 0, stream>>>(bsum, nb);
    fill_col<<<4096, 256, 0, stream>>>(ei, ei + E, rowptr, bsum, cur, col, E);

    // ---- h = x @ lin_w + lin_b ----
    gemm_128<<<gemm_grid, 256, 0, stream>>>(x, lin_w, lin_b, A, N, 0);

    for (int l = 0; l < 3; l++) {
        // z_pre = h + segment_sum(h[src], dst)   (gather via CSR)
        gather_agg<<<8192, 256, 0, stream>>>(A, rowptr, bsum, deg, col, B, N);
        // z = z_pre @ W1[l] + b1[l]   (in-place)
        gemm_128<<<gemm_grid, 256, 0, stream>>>(B, W1 + (size_t)l * 128 * 128,
                                                b1 + (size_t)l * 128, B, N, 0);
        // batch-norm (training stats) + relu, in-place
        hipMemsetAsync(stats, 0, 256 * sizeof(float), stream);
        bn_stats<<<1024, 256, 0, stream>>>(B, stats, N);
        bn_apply_relu<<<4096, 256, 0, stream>>>(B, stats, gamma + (size_t)l * 128,
                                                beta + (size_t)l * 128, N, invN);
        // h = relu(z @ W2[l] + b2[l])  -> back into A
        gemm_128<<<gemm_grid, 256, 0, stream>>>(B, W2 + (size_t)l * 128 * 128,
                                                b2 + (size_t)l * 128, A, N, 1);
    }

    // pred = rowwise dot of endpoint embeddings
    edge_dot<<<8192, 256, 0, stream>>>(A, eli, eli + EL, out, EL);
}

// Round 3
// 1199.702 us; speedup vs baseline: 7.3213x; 1.0694x over previous
//
#include <hip/hip_runtime.h>

// ===========================================================================
// GIN link-pred pipeline. R2->R3: fp32 vector GEMMs replaced by bf16x2-split
// MFMA GEMMs (A=A_hi+A_lo, W=W_hi+W_lo, 3x mfma_f32_16x16x32_bf16 => ~fp32
// accuracy at matrix-core rate). BN stats fused into gemm1 epilogue (block
// partials + finalize), BN apply+relu fused into gemm2 staging. h stays fp32
// (error budget reserved). gather_agg/edge_dot/CSR unchanged from R2.
// ===========================================================================

typedef __attribute__((ext_vector_type(8))) short short8v;
typedef __attribute__((ext_vector_type(4))) float float4v;

__device__ __forceinline__ unsigned short f2bf(float f) {
    union { float f; unsigned u; } v; v.f = f;
    unsigned u = v.u;
    unsigned r = u + 0x7fffu + ((u >> 16) & 1u);   // RNE
    return (unsigned short)(r >> 16);
}
__device__ __forceinline__ float bf2f(unsigned short h) {
    union { unsigned u; float f; } v; v.u = ((unsigned)h) << 16;
    return v.f;
}

// ---------------------------------------------------------------------------
// Weight prep: 7 128x128 matrices -> transposed (n-major) bf16 hi/lo splits.
// m=0: lin_w; m=1..3: W1[l]; m=4..6: W2[l].
// ---------------------------------------------------------------------------
__global__ __launch_bounds__(256) void prep_w(
    const float* __restrict__ lin_w, const float* __restrict__ W1,
    const float* __restrict__ W2,
    unsigned short* __restrict__ wt_hi, unsigned short* __restrict__ wt_lo)
{
    int idx = blockIdx.x * 256 + threadIdx.x;
    if (idx >= 7 * 16384) return;
    int m = idx >> 14;
    int r = idx & 16383;          // r = k*128 + n (source row-major)
    int k = r >> 7, n = r & 127;
    const float* src = (m == 0) ? lin_w
                     : (m <= 3) ? W1 + (size_t)(m - 1) * 16384
                                : W2 + (size_t)(m - 4) * 16384;
    float w = src[r];
    unsigned short hi = f2bf(w);
    unsigned short lo = f2bf(w - bf2f(hi));
    wt_hi[(size_t)m * 16384 + n * 128 + k] = hi;   // [n][k]
    wt_lo[(size_t)m * 16384 + n * 128 + k] = lo;
}

// ---------------------------------------------------------------------------
// MFMA GEMM: out[N,128] = act(bn(A[N,128]) @ W[128,128] + bias)
// flags: 1 = apply scale/shift+relu to INPUT during staging (BN apply)
//        2 = relu on OUTPUT
//        4 = emit per-block column sum/sumsq partials (BN stats, pre-act z)
// Block: 256 thr = 4 waves; tile 64 rows x 128 cols; wave w -> rows w*16..+15.
// LDS A tile stored as bf16 hi/lo, row stride 136 (pad 8 -> 2-way bank alias
// only). W read from global (n-major bf16), L2-hot. In-place safe (out==A).
// ---------------------------------------------------------------------------
__global__ __launch_bounds__(256) void gemm_mfma(
    const float* __restrict__ Ain,
    const unsigned short* __restrict__ Wh, const unsigned short* __restrict__ Wl,
    const float* __restrict__ bias, const float* __restrict__ ss,  // scale[128],shift[128]
    float* __restrict__ outp, float* __restrict__ part,            // [256][gridDim]
    int N, int flags)
{
    __shared__ __align__(16) unsigned short As[2][64][136];
    __shared__ float sstat[256];
    const int tid = threadIdx.x;
    const int row0 = blockIdx.x * 64;

    // ---- stage A tile (fp32 -> optional BN+relu -> bf16 hi/lo) ----
    for (int i = tid; i < 64 * 32; i += 256) {
        const int r = i >> 5, c4 = i & 31;
        const int row = row0 + r;
        float4 v = make_float4(0.f, 0.f, 0.f, 0.f);
        if (row < N) v = ((const float4*)(Ain + (size_t)row * 128))[c4];
        if (flags & 1) {
            const float4 sc = ((const float4*)ss)[c4];
            const float4 sh = ((const float4*)(ss + 128))[c4];
            v.x = fmaxf(v.x * sc.x + sh.x, 0.f);
            v.y = fmaxf(v.y * sc.y + sh.y, 0.f);
            v.z = fmaxf(v.z * sc.z + sh.z, 0.f);
            v.w = fmaxf(v.w * sc.w + sh.w, 0.f);
        }
        unsigned short h0 = f2bf(v.x), h1 = f2bf(v.y), h2 = f2bf(v.z), h3 = f2bf(v.w);
        unsigned short l0 = f2bf(v.x - bf2f(h0)), l1 = f2bf(v.y - bf2f(h1));
        unsigned short l2 = f2bf(v.z - bf2f(h2)), l3 = f2bf(v.w - bf2f(h3));
        uint2 uh, ul;
        uh.x = (unsigned)h0 | ((unsigned)h1 << 16);
        uh.y = (unsigned)h2 | ((unsigned)h3 << 16);
        ul.x = (unsigned)l0 | ((unsigned)l1 << 16);
        ul.y = (unsigned)l2 | ((unsigned)l3 << 16);
        *(uint2*)&As[0][r][c4 * 4] = uh;
        *(uint2*)&As[1][r][c4 * 4] = ul;
    }
    if (flags & 4) sstat[tid] = 0.f;
    __syncthreads();

    const int w    = tid >> 6;
    const int lane = tid & 63;
    const int ln   = lane & 15;   // col within 16-tile / row within A sub-tile
    const int lq   = lane >> 4;   // quad

    float4v acc[8];
    #pragma unroll
    for (int nt = 0; nt < 8; nt++) {
        const float bv = bias[nt * 16 + ln];
        acc[nt] = (float4v){bv, bv, bv, bv};
    }

    #pragma unroll
    for (int kc = 0; kc < 4; kc++) {
        const short8v ah = *(const short8v*)&As[0][w * 16 + ln][kc * 32 + lq * 8];
        const short8v al = *(const short8v*)&As[1][w * 16 + ln][kc * 32 + lq * 8];
        #pragma unroll
        for (int nt = 0; nt < 8; nt++) {
            const size_t boff = (size_t)(nt * 16 + ln) * 128 + kc * 32 + lq * 8;
            const short8v bh = *(const short8v*)&Wh[boff];
            const short8v bl = *(const short8v*)&Wl[boff];
            acc[nt] = __builtin_amdgcn_mfma_f32_16x16x32_bf16(ah, bh, acc[nt], 0, 0, 0);
            acc[nt] = __builtin_amdgcn_mfma_f32_16x16x32_bf16(ah, bl, acc[nt], 0, 0, 0);
            acc[nt] = __builtin_amdgcn_mfma_f32_16x16x32_bf16(al, bh, acc[nt], 0, 0, 0);
        }
    }

    // ---- store (C/D layout: col=lane&15, row=quad*4+reg) ----
    #pragma unroll
    for (int nt = 0; nt < 8; nt++) {
        const int colv = nt * 16 + ln;
        #pragma unroll
        for (int i = 0; i < 4; i++) {
            const int row = row0 + w * 16 + lq * 4 + i;
            if (row < N) {
                float v = acc[nt][i];
                if (flags & 2) v = fmaxf(v, 0.f);
                outp[(size_t)row * 128 + colv] = v;
            }
        }
    }

    // ---- BN stats partials (on pre-activation z) ----
    if (flags & 4) {
        #pragma unroll
        for (int nt = 0; nt < 8; nt++) {
            float s = 0.f, q = 0.f;
            #pragma unroll
            for (int i = 0; i < 4; i++) {
                const int row = row0 + w * 16 + lq * 4 + i;
                if (row < N) { const float v = acc[nt][i]; s += v; q += v * v; }
            }
            s += __shfl_xor(s, 16); s += __shfl_xor(s, 32);
            q += __shfl_xor(q, 16); q += __shfl_xor(q, 32);
            if (lane < 16) {
                atomicAdd(&sstat[nt * 16 + ln], s);
                atomicAdd(&sstat[128 + nt * 16 + ln], q);
            }
        }
        __syncthreads();
        part[(size_t)tid * gridDim.x + blockIdx.x] = sstat[tid];
    }
}

// ---------------------------------------------------------------------------
// BN finalize: reduce per-block partials -> scale[c], shift[c].
// grid = 128 blocks (one per channel), 256 threads.
// ---------------------------------------------------------------------------
__global__ __launch_bounds__(256) void bn_finalize(
    const float* __restrict__ part, int nblk, float invN,
    const float* __restrict__ gamma, const float* __restrict__ beta,
    float* __restrict__ ss)
{
    __shared__ float shs[256], shq[256];
    const int c = blockIdx.x, t = threadIdx.x;
    float s = 0.f, q = 0.f;
    for (int b = t; b < nblk; b += 256) {
        s += part[(size_t)c * nblk + b];
        q += part[(size_t)(128 + c) * nblk + b];
    }
    shs[t] = s; shq[t] = q;
    __syncthreads();
    for (int o = 128; o > 0; o >>= 1) {
        if (t < o) { shs[t] += shs[t + o]; shq[t] += shq[t + o]; }
        __syncthreads();
    }
    if (t == 0) {
        const float mu = shs[0] * invN;
        const float var = shq[0] * invN - mu * mu;
        const float sc = rsqrtf(fmaxf(var, 0.f) + 1e-5f) * gamma[c];
        ss[c] = sc;
        ss[128 + c] = beta[c] - mu * sc;
    }
}

// ---------------------------------------------------------------------------
// CSR build (unchanged from R2)
// ---------------------------------------------------------------------------
__global__ __launch_bounds__(256) void hist_deg(
    const int* __restrict__ dst, int* __restrict__ deg, int E)
{
    const int stride = gridDim.x * blockDim.x;
    for (int e = blockIdx.x * blockDim.x + threadIdx.x; e < E; e += stride)
        atomicAdd(&deg[dst[e]], 1);
}

__global__ __launch_bounds__(256) void scan_local(
    const int* __restrict__ deg, int* __restrict__ rowptr,
    int* __restrict__ bsum, int N)
{
    __shared__ int sh[256];
    const int t = threadIdx.x;
    const int base = blockIdx.x * 1024 + t * 4;
    int v[4], s = 0;
    #pragma unroll
    for (int k = 0; k < 4; k++) {
        v[k] = (base + k < N) ? deg[base + k] : 0;
        s += v[k];
    }
    sh[t] = s;
    __syncthreads();
    for (int off = 1; off < 256; off <<= 1) {
        int x = (t >= off) ? sh[t - off] : 0;
        __syncthreads();
        sh[t] += x;
        __syncthreads();
    }
    int run = sh[t] - s;
    #pragma unroll
    for (int k = 0; k < 4; k++) {
        if (base + k < N) rowptr[base + k] = run;
        run += v[k];
    }
    if (t == 255) bsum[blockIdx.x] = sh[255];
}

__global__ void scan_bsum(int* __restrict__ bsum, int nb)
{
    if (threadIdx.x == 0 && blockIdx.x == 0) {
        int acc = 0;
        for (int i = 0; i < nb; i++) {
            int t = bsum[i];
            bsum[i] = acc;
            acc += t;
        }
    }
}

__global__ __launch_bounds__(256) void fill_col(
    const int* __restrict__ src, const int* __restrict__ dst,
    const int* __restrict__ rowptr, const int* __restrict__ bsum,
    int* __restrict__ cur, int* __restrict__ col, int E)
{
    const int stride = gridDim.x * blockDim.x;
    for (int e = blockIdx.x * blockDim.x + threadIdx.x; e < E; e += stride) {
        const int d = dst[e];
        const int p = atomicAdd(&cur[d], 1);
        col[rowptr[d] + bsum[d >> 10] + p] = src[e];
    }
}

// ---------------------------------------------------------------------------
// Fused aggregation: out[i] = h[i] + sum_{j in CSR(i)} h[col[j]]  (fp32)
// ---------------------------------------------------------------------------
__global__ __launch_bounds__(256) void gather_agg(
    const float* __restrict__ h, const int* __restrict__ rowptr,
    const int* __restrict__ bsum, const int* __restrict__ deg,
    const int* __restrict__ col, float* __restrict__ out, int N)
{
    const long long total = (long long)N * 32;
    const int stride = gridDim.x * blockDim.x;
    for (long long i = (long long)blockIdx.x * blockDim.x + threadIdx.x; i < total; i += stride) {
        const int node = (int)(i >> 5);
        const int lane = (int)(i & 31);
        const int start = rowptr[node] + bsum[node >> 10];
        const int cnt = deg[node];
        float4 v = ((const float4*)(h + (size_t)node * 128))[lane];
        for (int j = 0; j < cnt; j++) {
            const int c = col[start + j];
            const float4 u = ((const float4*)(h + (size_t)c * 128))[lane];
            v.x += u.x; v.y += u.y; v.z += u.z; v.w += u.w;
        }
        ((float4*)(out + (size_t)node * 128))[lane] = v;
    }
}

// ---------------------------------------------------------------------------
// Classifier: out[e] = dot(h[ia[e]], h[ib[e]])
// ---------------------------------------------------------------------------
__global__ __launch_bounds__(256) void edge_dot(
    const float* __restrict__ h, const int* __restrict__ ia,
    const int* __restrict__ ib, float* __restrict__ out, int EL)
{
    const int stride = gridDim.x * blockDim.x;
    const long long total = (long long)EL * 32;
    for (long long i = (long long)blockIdx.x * blockDim.x + threadIdx.x; i < total; i += stride) {
        const int e = (int)(i >> 5);
        const int l = (int)(i & 31);
        const int a = ia[e];
        const int b = ib[e];
        const float4 va = ((const float4*)(h + (size_t)a * 128))[l];
        const float4 vb = ((const float4*)(h + (size_t)b * 128))[l];
        float d = va.x * vb.x + va.y * vb.y + va.z * vb.z + va.w * vb.w;
        #pragma unroll
        for (int off = 16; off > 0; off >>= 1) d += __shfl_xor(d, off);
        if (l == 0) out[e] = d;
    }
}

extern "C" void kernel_launch(void* const* d_in, const int* in_sizes, int n_in,
                              void* d_out, int out_size, void* d_ws, size_t ws_size,
                              hipStream_t stream)
{
    const float* x     = (const float*)d_in[0];
    const float* lin_w = (const float*)d_in[1];
    const float* lin_b = (const float*)d_in[2];
    const float* W1    = (const float*)d_in[3];
    const float* b1    = (const float*)d_in[4];
    const float* gamma = (const float*)d_in[5];
    const float* beta  = (const float*)d_in[6];
    const float* W2    = (const float*)d_in[7];
    const float* b2    = (const float*)d_in[8];
    const int*   ei    = (const int*)d_in[9];
    const int*   eli   = (const int*)d_in[10];
    float* out = (float*)d_out;

    const int N  = in_sizes[0] / 128;
    const int E  = in_sizes[9] / 2;
    const int EL = in_sizes[10] / 2;
    const size_t nd = (size_t)N * 128;
    const int nb = (N + 1023) / 1024;
    const int gemm_grid = (N + 63) / 64;

    // ws: A | B | deg | rowptr | cur | bsum | col | wt_hi | wt_lo | part | ss
    float* A      = (float*)d_ws;
    float* B      = A + nd;
    int*   deg    = (int*)(B + nd);
    int*   rowptr = deg + N;
    int*   cur    = rowptr + N;
    int*   bsum   = cur + N;
    int*   col    = bsum + nb;
    unsigned short* wt_hi = (unsigned short*)(col + E);
    unsigned short* wt_lo = wt_hi + 7 * 16384;
    float* part   = (float*)(wt_lo + 7 * 16384);
    float* ss     = part + (size_t)256 * gemm_grid;

    const float invN = 1.0f / (float)N;

    // ---- weight prep + CSR build ----
    prep_w<<<448, 256, 0, stream>>>(lin_w, W1, W2, wt_hi, wt_lo);
    hipMemsetAsync(deg, 0, (size_t)N * sizeof(int), stream);
    hipMemsetAsync(cur, 0, (size_t)N * sizeof(int), stream);
    hist_deg<<<4096, 256, 0, stream>>>(ei + E, deg, E);
    scan_local<<<nb, 256, 0, stream>>>(deg, rowptr, bsum, N);
    scan_bsum<<<1, 64, 0, stream>>>(bsum, nb);
    fill_col<<<4096, 256, 0, stream>>>(ei, ei + E, rowptr, bsum, cur, col, E);

    // ---- h = x @ lin_w + lin_b ----
    gemm_mfma<<<gemm_grid, 256, 0, stream>>>(x, wt_hi, wt_lo, lin_b, ss, A, part, N, 0);

    for (int l = 0; l < 3; l++) {
        const unsigned short* w1h = wt_hi + (size_t)(1 + l) * 16384;
        const unsigned short* w1l = wt_lo + (size_t)(1 + l) * 16384;
        const unsigned short* w2h = wt_hi + (size_t)(4 + l) * 16384;
        const unsigned short* w2l = wt_lo + (size_t)(4 + l) * 16384;
        // z_pre = h + agg  (fp32 gather)
        gather_agg<<<8192, 256, 0, stream>>>(A, rowptr, bsum, deg, col, B, N);
        // z = z_pre @ W1 + b1  (in-place, emit BN partials)
        gemm_mfma<<<gemm_grid, 256, 0, stream>>>(B, w1h, w1l, b1 + (size_t)l * 128,
                                                 ss, B, part, N, 4);
        bn_finalize<<<128, 256, 0, stream>>>(part, gemm_grid, invN,
                                             gamma + (size_t)l * 128,
                                             beta + (size_t)l * 128, ss);
        // h = relu(bn(z) @ W2 + b2)  (BN+relu fused into staging)
        gemm_mfma<<<gemm_grid, 256, 0, stream>>>(B, w2h, w2l, b2 + (size_t)l * 128,
                                                 ss, A, part, N, 1 | 2);
    }

    edge_dot<<<8192, 256, 0, stream>>>(A, eli, eli + EL, out, EL);
}

// Round 4
// 782.770 us; speedup vs baseline: 11.2209x; 1.5326x over previous
//
#include <hip/hip_runtime.h>

// ===========================================================================
// GIN link-pred. R3->R4:
//  - bf16 shadow h (written by h-producing GEMM epilogues); gather_agg and
//    edge_dot read bf16 rows (halves their random-read traffic; R3 showed
//    gather fetching 401 MB/dispatch at 45% HBM peak).
//  - GEMM waves split columns (acc[4][2]: 64 rows x 32 cols/wave) instead of
//    rows: 4x less B-operand L2 traffic, B loads amortized over 4 m-tiles,
//    BN partials without LDS atomics (wave owns its columns).
//  - fill_col write-amplification (107 MB for 6.4 MB payload) deferred.
// ===========================================================================

typedef __attribute__((ext_vector_type(8))) short short8v;
typedef __attribute__((ext_vector_type(4))) float float4v;

__device__ __forceinline__ unsigned short f2bf(float f) {
    union { float f; unsigned u; } v; v.f = f;
    unsigned u = v.u;
    unsigned r = u + 0x7fffu + ((u >> 16) & 1u);   // RNE
    return (unsigned short)(r >> 16);
}
__device__ __forceinline__ float bf2f(unsigned short h) {
    union { unsigned u; float f; } v; v.u = ((unsigned)h) << 16;
    return v.f;
}
__device__ __forceinline__ float bfu_lo(unsigned u) {
    union { unsigned v; float f; } x; x.v = u << 16; return x.f;
}
__device__ __forceinline__ float bfu_hi(unsigned u) {
    union { unsigned v; float f; } x; x.v = u & 0xffff0000u; return x.f;
}

// ---------------------------------------------------------------------------
// Weight prep: 7 128x128 fp32 -> transposed (n-major) bf16 hi/lo splits.
// ---------------------------------------------------------------------------
__global__ __launch_bounds__(256) void prep_w(
    const float* __restrict__ lin_w, const float* __restrict__ W1,
    const float* __restrict__ W2,
    unsigned short* __restrict__ wt_hi, unsigned short* __restrict__ wt_lo)
{
    int idx = blockIdx.x * 256 + threadIdx.x;
    if (idx >= 7 * 16384) return;
    int m = idx >> 14;
    int r = idx & 16383;          // r = k*128 + n
    int k = r >> 7, n = r & 127;
    const float* src = (m == 0) ? lin_w
                     : (m <= 3) ? W1 + (size_t)(m - 1) * 16384
                                : W2 + (size_t)(m - 4) * 16384;
    float w = src[r];
    unsigned short hi = f2bf(w);
    unsigned short lo = f2bf(w - bf2f(hi));
    wt_hi[(size_t)m * 16384 + n * 128 + k] = hi;   // [n][k]
    wt_lo[(size_t)m * 16384 + n * 128 + k] = lo;
}

// ---------------------------------------------------------------------------
// MFMA GEMM: out[N,128] = act(bn(A[N,128]) @ W + bias), bf16x2 split (3 MFMA).
// flags: 1=BN apply+relu on input staging, 2=relu out, 4=BN stats partials,
//        8=write bf16 shadow out.
// Block 256 thr = 4 waves, tile 64x128. Wave w -> cols w*32..w*32+31, all 64
// rows (acc[4][2]). LDS A tile bf16 hi/lo, stride 136 (2-way alias = free).
// In-place safe (out==A).
// ---------------------------------------------------------------------------
__global__ __launch_bounds__(256) void gemm_mfma(
    const float* __restrict__ Ain,
    const unsigned short* __restrict__ Wh, const unsigned short* __restrict__ Wl,
    const float* __restrict__ bias, const float* __restrict__ ss,
    float* __restrict__ outp, unsigned short* __restrict__ outb,
    float* __restrict__ part, int N, int flags)
{
    __shared__ __align__(16) unsigned short As[2][64][136];
    const int tid = threadIdx.x;
    const int row0 = blockIdx.x * 64;

    // ---- stage A tile (fp32 -> optional BN+relu -> bf16 hi/lo) ----
    for (int i = tid; i < 64 * 32; i += 256) {
        const int r = i >> 5, c4 = i & 31;
        const int row = row0 + r;
        float4 v = make_float4(0.f, 0.f, 0.f, 0.f);
        if (row < N) v = ((const float4*)(Ain + (size_t)row * 128))[c4];
        if (flags & 1) {
            const float4 sc = ((const float4*)ss)[c4];
            const float4 sh = ((const float4*)(ss + 128))[c4];
            v.x = fmaxf(v.x * sc.x + sh.x, 0.f);
            v.y = fmaxf(v.y * sc.y + sh.y, 0.f);
            v.z = fmaxf(v.z * sc.z + sh.z, 0.f);
            v.w = fmaxf(v.w * sc.w + sh.w, 0.f);
        }
        unsigned short h0 = f2bf(v.x), h1 = f2bf(v.y), h2 = f2bf(v.z), h3 = f2bf(v.w);
        unsigned short l0 = f2bf(v.x - bf2f(h0)), l1 = f2bf(v.y - bf2f(h1));
        unsigned short l2 = f2bf(v.z - bf2f(h2)), l3 = f2bf(v.w - bf2f(h3));
        uint2 uh, ul;
        uh.x = (unsigned)h0 | ((unsigned)h1 << 16);
        uh.y = (unsigned)h2 | ((unsigned)h3 << 16);
        ul.x = (unsigned)l0 | ((unsigned)l1 << 16);
        ul.y = (unsigned)l2 | ((unsigned)l3 << 16);
        *(uint2*)&As[0][r][c4 * 4] = uh;
        *(uint2*)&As[1][r][c4 * 4] = ul;
    }
    __syncthreads();

    const int w    = tid >> 6;
    const int lane = tid & 63;
    const int ln   = lane & 15;
    const int lq   = lane >> 4;
    const int c0   = w * 32;

    float4v acc[4][2];
    #pragma unroll
    for (int nt = 0; nt < 2; nt++) {
        const float bv = bias[c0 + nt * 16 + ln];
        #pragma unroll
        for (int mt = 0; mt < 4; mt++) acc[mt][nt] = (float4v){bv, bv, bv, bv};
    }

    #pragma unroll
    for (int kc = 0; kc < 4; kc++) {
        const size_t b0 = (size_t)(c0 + ln) * 128 + kc * 32 + lq * 8;
        const size_t b1 = (size_t)(c0 + 16 + ln) * 128 + kc * 32 + lq * 8;
        const short8v bh0 = *(const short8v*)&Wh[b0];
        const short8v bl0 = *(const short8v*)&Wl[b0];
        const short8v bh1 = *(const short8v*)&Wh[b1];
        const short8v bl1 = *(const short8v*)&Wl[b1];
        #pragma unroll
        for (int mt = 0; mt < 4; mt++) {
            const short8v ah = *(const short8v*)&As[0][mt * 16 + ln][kc * 32 + lq * 8];
            const short8v al = *(const short8v*)&As[1][mt * 16 + ln][kc * 32 + lq * 8];
            acc[mt][0] = __builtin_amdgcn_mfma_f32_16x16x32_bf16(ah, bh0, acc[mt][0], 0, 0, 0);
            acc[mt][0] = __builtin_amdgcn_mfma_f32_16x16x32_bf16(ah, bl0, acc[mt][0], 0, 0, 0);
            acc[mt][0] = __builtin_amdgcn_mfma_f32_16x16x32_bf16(al, bh0, acc[mt][0], 0, 0, 0);
            acc[mt][1] = __builtin_amdgcn_mfma_f32_16x16x32_bf16(ah, bh1, acc[mt][1], 0, 0, 0);
            acc[mt][1] = __builtin_amdgcn_mfma_f32_16x16x32_bf16(ah, bl1, acc[mt][1], 0, 0, 0);
            acc[mt][1] = __builtin_amdgcn_mfma_f32_16x16x32_bf16(al, bh1, acc[mt][1], 0, 0, 0);
        }
    }

    // ---- store (C/D: col=lane&15, row=quad*4+reg) ----
    #pragma unroll
    for (int mt = 0; mt < 4; mt++) {
        #pragma unroll
        for (int nt = 0; nt < 2; nt++) {
            const int colv = c0 + nt * 16 + ln;
            #pragma unroll
            for (int i = 0; i < 4; i++) {
                const int row = row0 + mt * 16 + lq * 4 + i;
                if (row < N) {
                    float v = acc[mt][nt][i];
                    if (flags & 2) v = fmaxf(v, 0.f);
                    outp[(size_t)row * 128 + colv] = v;
                    if (flags & 8) outb[(size_t)row * 128 + colv] = f2bf(v);
                }
            }
        }
    }

    // ---- BN stats partials (pre-activation z); wave owns its 32 cols ----
    if (flags & 4) {
        #pragma unroll
        for (int nt = 0; nt < 2; nt++) {
            float s = 0.f, q = 0.f;
            #pragma unroll
            for (int mt = 0; mt < 4; mt++) {
                #pragma unroll
                for (int i = 0; i < 4; i++) {
                    const int row = row0 + mt * 16 + lq * 4 + i;
                    if (row < N) { const float v = acc[mt][nt][i]; s += v; q += v * v; }
                }
            }
            s += __shfl_xor(s, 16); s += __shfl_xor(s, 32);
            q += __shfl_xor(q, 16); q += __shfl_xor(q, 32);
            if (lq == 0) {
                const int colv = c0 + nt * 16 + ln;
                part[(size_t)colv * gridDim.x + blockIdx.x] = s;
                part[(size_t)(128 + colv) * gridDim.x + blockIdx.x] = q;
            }
        }
    }
}

// ---------------------------------------------------------------------------
// BN finalize: reduce partials -> scale[c], shift[c]. grid=128 (1/channel).
// ---------------------------------------------------------------------------
__global__ __launch_bounds__(256) void bn_finalize(
    const float* __restrict__ part, int nblk, float invN,
    const float* __restrict__ gamma, const float* __restrict__ beta,
    float* __restrict__ ss)
{
    __shared__ float shs[256], shq[256];
    const int c = blockIdx.x, t = threadIdx.x;
    float s = 0.f, q = 0.f;
    for (int b = t; b < nblk; b += 256) {
        s += part[(size_t)c * nblk + b];
        q += part[(size_t)(128 + c) * nblk + b];
    }
    shs[t] = s; shq[t] = q;
    __syncthreads();
    for (int o = 128; o > 0; o >>= 1) {
        if (t < o) { shs[t] += shs[t + o]; shq[t] += shq[t + o]; }
        __syncthreads();
    }
    if (t == 0) {
        const float mu = shs[0] * invN;
        const float var = shq[0] * invN - mu * mu;
        const float sc = rsqrtf(fmaxf(var, 0.f) + 1e-5f) * gamma[c];
        ss[c] = sc;
        ss[128 + c] = beta[c] - mu * sc;
    }
}

// ---------------------------------------------------------------------------
// CSR build
// ---------------------------------------------------------------------------
__global__ __launch_bounds__(256) void hist_deg(
    const int* __restrict__ dst, int* __restrict__ deg, int E)
{
    const int stride = gridDim.x * blockDim.x;
    for (int e = blockIdx.x * blockDim.x + threadIdx.x; e < E; e += stride)
        atomicAdd(&deg[dst[e]], 1);
}

__global__ __launch_bounds__(256) void scan_local(
    const int* __restrict__ deg, int* __restrict__ rowptr,
    int* __restrict__ bsum, int N)
{
    __shared__ int sh[256];
    const int t = threadIdx.x;
    const int base = blockIdx.x * 1024 + t * 4;
    int v[4], s = 0;
    #pragma unroll
    for (int k = 0; k < 4; k++) {
        v[k] = (base + k < N) ? deg[base + k] : 0;
        s += v[k];
    }
    sh[t] = s;
    __syncthreads();
    for (int off = 1; off < 256; off <<= 1) {
        int x = (t >= off) ? sh[t - off] : 0;
        __syncthreads();
        sh[t] += x;
        __syncthreads();
    }
    int run = sh[t] - s;
    #pragma unroll
    for (int k = 0; k < 4; k++) {
        if (base + k < N) rowptr[base + k] = run;
        run += v[k];
    }
    if (t == 255) bsum[blockIdx.x] = sh[255];
}

__global__ void scan_bsum(int* __restrict__ bsum, int nb)
{
    if (threadIdx.x == 0 && blockIdx.x == 0) {
        int acc = 0;
        for (int i = 0; i < nb; i++) {
            int t = bsum[i];
            bsum[i] = acc;
            acc += t;
        }
    }
}

__global__ __launch_bounds__(256) void fill_col(
    const int* __restrict__ src, const int* __restrict__ dst,
    const int* __restrict__ rowptr, const int* __restrict__ bsum,
    int* __restrict__ cur, int* __restrict__ col, int E)
{
    const int stride = gridDim.x * blockDim.x;
    for (int e = blockIdx.x * blockDim.x + threadIdx.x; e < E; e += stride) {
        const int d = dst[e];
        const int p = atomicAdd(&cur[d], 1);
        col[rowptr[d] + bsum[d >> 10] + p] = src[e];
    }
}

// ---------------------------------------------------------------------------
// Aggregation: out[i] = h[i] (fp32) + sum_j hb[col[j]] (bf16 neighbors).
// 16 lanes per node, 16 B (8 bf16) per lane per neighbor row.
// ---------------------------------------------------------------------------
__global__ __launch_bounds__(256) void gather_agg(
    const float* __restrict__ h, const unsigned short* __restrict__ hb,
    const int* __restrict__ rowptr, const int* __restrict__ bsum,
    const int* __restrict__ deg, const int* __restrict__ col,
    float* __restrict__ out, int N)
{
    const long long total = (long long)N * 16;
    const int stride = gridDim.x * blockDim.x;
    for (long long i = (long long)blockIdx.x * blockDim.x + threadIdx.x; i < total; i += stride) {
        const int node = (int)(i >> 4);
        const int lane = (int)(i & 15);
        const int start = rowptr[node] + bsum[node >> 10];
        const int cnt = deg[node];
        float4 a0 = ((const float4*)(h + (size_t)node * 128))[lane * 2];
        float4 a1 = ((const float4*)(h + (size_t)node * 128))[lane * 2 + 1];
        for (int j = 0; j < cnt; j++) {
            const int c = col[start + j];
            const uint4 u = *(const uint4*)(hb + (size_t)c * 128 + lane * 8);
            a0.x += bfu_lo(u.x); a0.y += bfu_hi(u.x);
            a0.z += bfu_lo(u.y); a0.w += bfu_hi(u.y);
            a1.x += bfu_lo(u.z); a1.y += bfu_hi(u.z);
            a1.z += bfu_lo(u.w); a1.w += bfu_hi(u.w);
        }
        ((float4*)(out + (size_t)node * 128))[lane * 2] = a0;
        ((float4*)(out + (size_t)node * 128))[lane * 2 + 1] = a1;
    }
}

// ---------------------------------------------------------------------------
// Classifier: out[e] = dot(hb[ia[e]], hb[ib[e]]), bf16 reads, fp32 math.
// 16 lanes per edge.
// ---------------------------------------------------------------------------
__global__ __launch_bounds__(256) void edge_dot(
    const unsigned short* __restrict__ hb, const int* __restrict__ ia,
    const int* __restrict__ ib, float* __restrict__ out, int EL)
{
    const int stride = gridDim.x * blockDim.x;
    const long long total = (long long)EL * 16;
    for (long long i = (long long)blockIdx.x * blockDim.x + threadIdx.x; i < total; i += stride) {
        const int e = (int)(i >> 4);
        const int l = (int)(i & 15);
        const int a = ia[e];
        const int b = ib[e];
        const uint4 u = *(const uint4*)(hb + (size_t)a * 128 + l * 8);
        const uint4 v = *(const uint4*)(hb + (size_t)b * 128 + l * 8);
        float d = bfu_lo(u.x) * bfu_lo(v.x) + bfu_hi(u.x) * bfu_hi(v.x)
                + bfu_lo(u.y) * bfu_lo(v.y) + bfu_hi(u.y) * bfu_hi(v.y)
                + bfu_lo(u.z) * bfu_lo(v.z) + bfu_hi(u.z) * bfu_hi(v.z)
                + bfu_lo(u.w) * bfu_lo(v.w) + bfu_hi(u.w) * bfu_hi(v.w);
        d += __shfl_xor(d, 1); d += __shfl_xor(d, 2);
        d += __shfl_xor(d, 4); d += __shfl_xor(d, 8);
        if (l == 0) out[e] = d;
    }
}

extern "C" void kernel_launch(void* const* d_in, const int* in_sizes, int n_in,
                              void* d_out, int out_size, void* d_ws, size_t ws_size,
                              hipStream_t stream)
{
    const float* x     = (const float*)d_in[0];
    const float* lin_w = (const float*)d_in[1];
    const float* lin_b = (const float*)d_in[2];
    const float* W1    = (const float*)d_in[3];
    const float* b1    = (const float*)d_in[4];
    const float* gamma = (const float*)d_in[5];
    const float* beta  = (const float*)d_in[6];
    const float* W2    = (const float*)d_in[7];
    const float* b2    = (const float*)d_in[8];
    const int*   ei    = (const int*)d_in[9];
    const int*   eli   = (const int*)d_in[10];
    float* out = (float*)d_out;

    const int N  = in_sizes[0] / 128;
    const int E  = in_sizes[9] / 2;
    const int EL = in_sizes[10] / 2;
    const size_t nd = (size_t)N * 128;
    const int nb = (N + 1023) / 1024;
    const int gemm_grid = (N + 63) / 64;

    // ws: A | B | hb | deg | rowptr | cur | bsum | col | wt_hi | wt_lo | part | ss
    float* A      = (float*)d_ws;
    float* B      = A + nd;
    unsigned short* hb = (unsigned short*)(B + nd);
    int*   deg    = (int*)(hb + nd);
    int*   rowptr = deg + N;
    int*   cur    = rowptr + N;
    int*   bsum   = cur + N;
    int*   col    = bsum + nb;
    unsigned short* wt_hi = (unsigned short*)(col + E);
    unsigned short* wt_lo = wt_hi + 7 * 16384;
    float* part   = (float*)(wt_lo + 7 * 16384);
    float* ss     = part + (size_t)256 * gemm_grid;

    const float invN = 1.0f / (float)N;

    // ---- weight prep + CSR build ----
    prep_w<<<448, 256, 0, stream>>>(lin_w, W1, W2, wt_hi, wt_lo);
    hipMemsetAsync(deg, 0, (size_t)N * sizeof(int), stream);
    hipMemsetAsync(cur, 0, (size_t)N * sizeof(int), stream);
    hist_deg<<<4096, 256, 0, stream>>>(ei + E, deg, E);
    scan_local<<<nb, 256, 0, stream>>>(deg, rowptr, bsum, N);
    scan_bsum<<<1, 64, 0, stream>>>(bsum, nb);
    fill_col<<<4096, 256, 0, stream>>>(ei, ei + E, rowptr, bsum, cur, col, E);

    // ---- h = x @ lin_w + lin_b  (write fp32 + bf16 shadow) ----
    gemm_mfma<<<gemm_grid, 256, 0, stream>>>(x, wt_hi, wt_lo, lin_b, ss, A, hb, part, N, 8);

    for (int l = 0; l < 3; l++) {
        const unsigned short* w1h = wt_hi + (size_t)(1 + l) * 16384;
        const unsigned short* w1l = wt_lo + (size_t)(1 + l) * 16384;
        const unsigned short* w2h = wt_hi + (size_t)(4 + l) * 16384;
        const unsigned short* w2l = wt_lo + (size_t)(4 + l) * 16384;
        // z_pre = h + agg (bf16 neighbor reads)
        gather_agg<<<8192, 256, 0, stream>>>(A, hb, rowptr, bsum, deg, col, B, N);
        // z = z_pre @ W1 + b1 (in-place, BN partials)
        gemm_mfma<<<gemm_grid, 256, 0, stream>>>(B, w1h, w1l, b1 + (size_t)l * 128,
                                                 ss, B, hb, part, N, 4);
        bn_finalize<<<128, 256, 0, stream>>>(part, gemm_grid, invN,
                                             gamma + (size_t)l * 128,
                                             beta + (size_t)l * 128, ss);
        // h = relu(bn(z) @ W2 + b2) -> A fp32 + hb shadow
        gemm_mfma<<<gemm_grid, 256, 0, stream>>>(B, w2h, w2l, b2 + (size_t)l * 128,
                                                 ss, A, hb, part, N, 1 | 2 | 8);
    }

    edge_dot<<<8192, 256, 0, stream>>>(hb, eli, eli + EL, out, EL);
}

// Round 5
// 743.009 us; speedup vs baseline: 11.8214x; 1.0535x over previous
//
#include <hip/hip_runtime.h>

// ===========================================================================
// GIN link-pred. R4->R5: gather_agg fused into gemm1's staging phase
// (z_pre = h + sum hb[col[j]] computed on the fly, split hi/lo into LDS;
// removes the 51 MB x2 z_pre round-trip per layer and 3 dispatches).
// flags: 1=BN apply+relu on staged input, 2=relu out, 4=BN stats partials,
//        8=write bf16 shadow, 16=skip fp32 out, 32=aggregate during staging.
// fill_col write-amplification (107 MB for 6.4 MB) still deferred.
// ===========================================================================

typedef __attribute__((ext_vector_type(8))) short short8v;
typedef __attribute__((ext_vector_type(4))) float float4v;

__device__ __forceinline__ unsigned short f2bf(float f) {
    union { float f; unsigned u; } v; v.f = f;
    unsigned u = v.u;
    unsigned r = u + 0x7fffu + ((u >> 16) & 1u);   // RNE
    return (unsigned short)(r >> 16);
}
__device__ __forceinline__ float bf2f(unsigned short h) {
    union { unsigned u; float f; } v; v.u = ((unsigned)h) << 16;
    return v.f;
}
__device__ __forceinline__ float bfu_lo(unsigned u) {
    union { unsigned v; float f; } x; x.v = u << 16; return x.f;
}
__device__ __forceinline__ float bfu_hi(unsigned u) {
    union { unsigned v; float f; } x; x.v = u & 0xffff0000u; return x.f;
}

// ---------------------------------------------------------------------------
// Weight prep: 7 128x128 fp32 -> transposed (n-major) bf16 hi/lo splits.
// ---------------------------------------------------------------------------
__global__ __launch_bounds__(256) void prep_w(
    const float* __restrict__ lin_w, const float* __restrict__ W1,
    const float* __restrict__ W2,
    unsigned short* __restrict__ wt_hi, unsigned short* __restrict__ wt_lo)
{
    int idx = blockIdx.x * 256 + threadIdx.x;
    if (idx >= 7 * 16384) return;
    int m = idx >> 14;
    int r = idx & 16383;          // r = k*128 + n
    int k = r >> 7, n = r & 127;
    const float* src = (m == 0) ? lin_w
                     : (m <= 3) ? W1 + (size_t)(m - 1) * 16384
                                : W2 + (size_t)(m - 4) * 16384;
    float w = src[r];
    unsigned short hi = f2bf(w);
    unsigned short lo = f2bf(w - bf2f(hi));
    wt_hi[(size_t)m * 16384 + n * 128 + k] = hi;   // [n][k]
    wt_lo[(size_t)m * 16384 + n * 128 + k] = lo;
}

// ---------------------------------------------------------------------------
// MFMA GEMM (+ optional fused neighbor aggregation in staging).
// out[N,128] = act(bn(stage(A))[N,128] @ W + bias), bf16x2 split (3 MFMA).
// Block 256 thr = 4 waves, tile 64x128. Wave w -> cols w*32..+31, all 64 rows
// (acc[4][2]). LDS A tile bf16 hi/lo, stride 136. In-place safe (out==A).
// ---------------------------------------------------------------------------
__global__ __launch_bounds__(256) void gemm_mfma(
    const float* __restrict__ Ain, const unsigned short* __restrict__ hbin,
    const int* __restrict__ rowptr, const int* __restrict__ bsum,
    const int* __restrict__ deg, const int* __restrict__ col,
    const unsigned short* __restrict__ Wh, const unsigned short* __restrict__ Wl,
    const float* __restrict__ bias, const float* __restrict__ ss,
    float* __restrict__ outp, unsigned short* __restrict__ outb,
    float* __restrict__ part, int N, int flags)
{
    __shared__ __align__(16) unsigned short As[2][64][136];
    const int tid = threadIdx.x;
    const int row0 = blockIdx.x * 64;

    if (flags & 32) {
        // ---- staging with fused aggregation: 16 groups x 16 lanes ----
        const int g = tid >> 4;
        const int l = tid & 15;
        #pragma unroll
        for (int rr = 0; rr < 4; rr++) {
            const int r = g + rr * 16;
            const int row = row0 + r;
            float4 a0 = make_float4(0.f, 0.f, 0.f, 0.f);
            float4 a1 = make_float4(0.f, 0.f, 0.f, 0.f);
            if (row < N) {
                a0 = ((const float4*)(Ain + (size_t)row * 128))[l * 2];
                a1 = ((const float4*)(Ain + (size_t)row * 128))[l * 2 + 1];
                const int start = rowptr[row] + bsum[row >> 10];
                const int cnt = deg[row];
                int j = 0;
                for (; j + 1 < cnt; j += 2) {
                    const int c0i = col[start + j];
                    const int c1i = col[start + j + 1];
                    const uint4 u0 = *(const uint4*)(hbin + (size_t)c0i * 128 + l * 8);
                    const uint4 u1 = *(const uint4*)(hbin + (size_t)c1i * 128 + l * 8);
                    a0.x += bfu_lo(u0.x); a0.y += bfu_hi(u0.x);
                    a0.z += bfu_lo(u0.y); a0.w += bfu_hi(u0.y);
                    a1.x += bfu_lo(u0.z); a1.y += bfu_hi(u0.z);
                    a1.z += bfu_lo(u0.w); a1.w += bfu_hi(u0.w);
                    a0.x += bfu_lo(u1.x); a0.y += bfu_hi(u1.x);
                    a0.z += bfu_lo(u1.y); a0.w += bfu_hi(u1.y);
                    a1.x += bfu_lo(u1.z); a1.y += bfu_hi(u1.z);
                    a1.z += bfu_lo(u1.w); a1.w += bfu_hi(u1.w);
                }
                if (j < cnt) {
                    const int c0i = col[start + j];
                    const uint4 u0 = *(const uint4*)(hbin + (size_t)c0i * 128 + l * 8);
                    a0.x += bfu_lo(u0.x); a0.y += bfu_hi(u0.x);
                    a0.z += bfu_lo(u0.y); a0.w += bfu_hi(u0.y);
                    a1.x += bfu_lo(u0.z); a1.y += bfu_hi(u0.z);
                    a1.z += bfu_lo(u0.w); a1.w += bfu_hi(u0.w);
                }
            }
            unsigned short h0 = f2bf(a0.x), h1 = f2bf(a0.y), h2 = f2bf(a0.z), h3 = f2bf(a0.w);
            unsigned short h4 = f2bf(a1.x), h5 = f2bf(a1.y), h6 = f2bf(a1.z), h7 = f2bf(a1.w);
            uint4 uh, ul;
            uh.x = (unsigned)h0 | ((unsigned)h1 << 16);
            uh.y = (unsigned)h2 | ((unsigned)h3 << 16);
            uh.z = (unsigned)h4 | ((unsigned)h5 << 16);
            uh.w = (unsigned)h6 | ((unsigned)h7 << 16);
            ul.x = (unsigned)f2bf(a0.x - bf2f(h0)) | ((unsigned)f2bf(a0.y - bf2f(h1)) << 16);
            ul.y = (unsigned)f2bf(a0.z - bf2f(h2)) | ((unsigned)f2bf(a0.w - bf2f(h3)) << 16);
            ul.z = (unsigned)f2bf(a1.x - bf2f(h4)) | ((unsigned)f2bf(a1.y - bf2f(h5)) << 16);
            ul.w = (unsigned)f2bf(a1.z - bf2f(h6)) | ((unsigned)f2bf(a1.w - bf2f(h7)) << 16);
            *(uint4*)&As[0][r][l * 8] = uh;
            *(uint4*)&As[1][r][l * 8] = ul;
        }
    } else {
        // ---- plain staging (optional BN apply + relu) ----
        for (int i = tid; i < 64 * 32; i += 256) {
            const int r = i >> 5, c4 = i & 31;
            const int row = row0 + r;
            float4 v = make_float4(0.f, 0.f, 0.f, 0.f);
            if (row < N) v = ((const float4*)(Ain + (size_t)row * 128))[c4];
            if (flags & 1) {
                const float4 sc = ((const float4*)ss)[c4];
                const float4 sh = ((const float4*)(ss + 128))[c4];
                v.x = fmaxf(v.x * sc.x + sh.x, 0.f);
                v.y = fmaxf(v.y * sc.y + sh.y, 0.f);
                v.z = fmaxf(v.z * sc.z + sh.z, 0.f);
                v.w = fmaxf(v.w * sc.w + sh.w, 0.f);
            }
            unsigned short h0 = f2bf(v.x), h1 = f2bf(v.y), h2 = f2bf(v.z), h3 = f2bf(v.w);
            unsigned short l0 = f2bf(v.x - bf2f(h0)), l1 = f2bf(v.y - bf2f(h1));
            unsigned short l2 = f2bf(v.z - bf2f(h2)), l3 = f2bf(v.w - bf2f(h3));
            uint2 uh, ul;
            uh.x = (unsigned)h0 | ((unsigned)h1 << 16);
            uh.y = (unsigned)h2 | ((unsigned)h3 << 16);
            ul.x = (unsigned)l0 | ((unsigned)l1 << 16);
            ul.y = (unsigned)l2 | ((unsigned)l3 << 16);
            *(uint2*)&As[0][r][c4 * 4] = uh;
            *(uint2*)&As[1][r][c4 * 4] = ul;
        }
    }
    __syncthreads();

    const int w    = tid >> 6;
    const int lane = tid & 63;
    const int ln   = lane & 15;
    const int lq   = lane >> 4;
    const int c0   = w * 32;

    float4v acc[4][2];
    #pragma unroll
    for (int nt = 0; nt < 2; nt++) {
        const float bv = bias[c0 + nt * 16 + ln];
        #pragma unroll
        for (int mt = 0; mt < 4; mt++) acc[mt][nt] = (float4v){bv, bv, bv, bv};
    }

    #pragma unroll
    for (int kc = 0; kc < 4; kc++) {
        const size_t b0 = (size_t)(c0 + ln) * 128 + kc * 32 + lq * 8;
        const size_t b1 = (size_t)(c0 + 16 + ln) * 128 + kc * 32 + lq * 8;
        const short8v bh0 = *(const short8v*)&Wh[b0];
        const short8v bl0 = *(const short8v*)&Wl[b0];
        const short8v bh1 = *(const short8v*)&Wh[b1];
        const short8v bl1 = *(const short8v*)&Wl[b1];
        #pragma unroll
        for (int mt = 0; mt < 4; mt++) {
            const short8v ah = *(const short8v*)&As[0][mt * 16 + ln][kc * 32 + lq * 8];
            const short8v al = *(const short8v*)&As[1][mt * 16 + ln][kc * 32 + lq * 8];
            acc[mt][0] = __builtin_amdgcn_mfma_f32_16x16x32_bf16(ah, bh0, acc[mt][0], 0, 0, 0);
            acc[mt][0] = __builtin_amdgcn_mfma_f32_16x16x32_bf16(ah, bl0, acc[mt][0], 0, 0, 0);
            acc[mt][0] = __builtin_amdgcn_mfma_f32_16x16x32_bf16(al, bh0, acc[mt][0], 0, 0, 0);
            acc[mt][1] = __builtin_amdgcn_mfma_f32_16x16x32_bf16(ah, bh1, acc[mt][1], 0, 0, 0);
            acc[mt][1] = __builtin_amdgcn_mfma_f32_16x16x32_bf16(ah, bl1, acc[mt][1], 0, 0, 0);
            acc[mt][1] = __builtin_amdgcn_mfma_f32_16x16x32_bf16(al, bh1, acc[mt][1], 0, 0, 0);
        }
    }

    // ---- store (C/D: col=lane&15, row=quad*4+reg) ----
    #pragma unroll
    for (int mt = 0; mt < 4; mt++) {
        #pragma unroll
        for (int nt = 0; nt < 2; nt++) {
            const int colv = c0 + nt * 16 + ln;
            #pragma unroll
            for (int i = 0; i < 4; i++) {
                const int row = row0 + mt * 16 + lq * 4 + i;
                if (row < N) {
                    float v = acc[mt][nt][i];
                    if (flags & 2) v = fmaxf(v, 0.f);
                    if (!(flags & 16)) outp[(size_t)row * 128 + colv] = v;
                    if (flags & 8) outb[(size_t)row * 128 + colv] = f2bf(v);
                }
            }
        }
    }

    // ---- BN stats partials (pre-activation z); wave owns its 32 cols ----
    if (flags & 4) {
        #pragma unroll
        for (int nt = 0; nt < 2; nt++) {
            float s = 0.f, q = 0.f;
            #pragma unroll
            for (int mt = 0; mt < 4; mt++) {
                #pragma unroll
                for (int i = 0; i < 4; i++) {
                    const int row = row0 + mt * 16 + lq * 4 + i;
                    if (row < N) { const float v = acc[mt][nt][i]; s += v; q += v * v; }
                }
            }
            s += __shfl_xor(s, 16); s += __shfl_xor(s, 32);
            q += __shfl_xor(q, 16); q += __shfl_xor(q, 32);
            if (lq == 0) {
                const int colv = c0 + nt * 16 + ln;
                part[(size_t)colv * gridDim.x + blockIdx.x] = s;
                part[(size_t)(128 + colv) * gridDim.x + blockIdx.x] = q;
            }
        }
    }
}

// ---------------------------------------------------------------------------
// BN finalize: reduce partials -> scale[c], shift[c]. grid=128 (1/channel).
// ---------------------------------------------------------------------------
__global__ __launch_bounds__(256) void bn_finalize(
    const float* __restrict__ part, int nblk, float invN,
    const float* __restrict__ gamma, const float* __restrict__ beta,
    float* __restrict__ ss)
{
    __shared__ float shs[256], shq[256];
    const int c = blockIdx.x, t = threadIdx.x;
    float s = 0.f, q = 0.f;
    for (int b = t; b < nblk; b += 256) {
        s += part[(size_t)c * nblk + b];
        q += part[(size_t)(128 + c) * nblk + b];
    }
    shs[t] = s; shq[t] = q;
    __syncthreads();
    for (int o = 128; o > 0; o >>= 1) {
        if (t < o) { shs[t] += shs[t + o]; shq[t] += shq[t + o]; }
        __syncthreads();
    }
    if (t == 0) {
        const float mu = shs[0] * invN;
        const float var = shq[0] * invN - mu * mu;
        const float sc = rsqrtf(fmaxf(var, 0.f) + 1e-5f) * gamma[c];
        ss[c] = sc;
        ss[128 + c] = beta[c] - mu * sc;
    }
}

// ---------------------------------------------------------------------------
// CSR build
// ---------------------------------------------------------------------------
__global__ __launch_bounds__(256) void hist_deg(
    const int* __restrict__ dst, int* __restrict__ deg, int E)
{
    const int stride = gridDim.x * blockDim.x;
    for (int e = blockIdx.x * blockDim.x + threadIdx.x; e < E; e += stride)
        atomicAdd(&deg[dst[e]], 1);
}

__global__ __launch_bounds__(256) void scan_local(
    const int* __restrict__ deg, int* __restrict__ rowptr,
    int* __restrict__ bsum, int N)
{
    __shared__ int sh[256];
    const int t = threadIdx.x;
    const int base = blockIdx.x * 1024 + t * 4;
    int v[4], s = 0;
    #pragma unroll
    for (int k = 0; k < 4; k++) {
        v[k] = (base + k < N) ? deg[base + k] : 0;
        s += v[k];
    }
    sh[t] = s;
    __syncthreads();
    for (int off = 1; off < 256; off <<= 1) {
        int x = (t >= off) ? sh[t - off] : 0;
        __syncthreads();
        sh[t] += x;
        __syncthreads();
    }
    int run = sh[t] - s;
    #pragma unroll
    for (int k = 0; k < 4; k++) {
        if (base + k < N) rowptr[base + k] = run;
        run += v[k];
    }
    if (t == 255) bsum[blockIdx.x] = sh[255];
}

__global__ void scan_bsum(int* __restrict__ bsum, int nb)
{
    if (threadIdx.x == 0 && blockIdx.x == 0) {
        int acc = 0;
        for (int i = 0; i < nb; i++) {
            int t = bsum[i];
            bsum[i] = acc;
            acc += t;
        }
    }
}

__global__ __launch_bounds__(256) void fill_col(
    const int* __restrict__ src, const int* __restrict__ dst,
    const int* __restrict__ rowptr, const int* __restrict__ bsum,
    int* __restrict__ cur, int* __restrict__ col, int E)
{
    const int stride = gridDim.x * blockDim.x;
    for (int e = blockIdx.x * blockDim.x + threadIdx.x; e < E; e += stride) {
        const int d = dst[e];
        const int p = atomicAdd(&cur[d], 1);
        col[rowptr[d] + bsum[d >> 10] + p] = src[e];
    }
}

// ---------------------------------------------------------------------------
// Classifier: out[e] = dot(hb[ia[e]], hb[ib[e]]), bf16 reads, fp32 math.
// ---------------------------------------------------------------------------
__global__ __launch_bounds__(256) void edge_dot(
    const unsigned short* __restrict__ hb, const int* __restrict__ ia,
    const int* __restrict__ ib, float* __restrict__ out, int EL)
{
    const int stride = gridDim.x * blockDim.x;
    const long long total = (long long)EL * 16;
    for (long long i = (long long)blockIdx.x * blockDim.x + threadIdx.x; i < total; i += stride) {
        const int e = (int)(i >> 4);
        const int l = (int)(i & 15);
        const int a = ia[e];
        const int b = ib[e];
        const uint4 u = *(const uint4*)(hb + (size_t)a * 128 + l * 8);
        const uint4 v = *(const uint4*)(hb + (size_t)b * 128 + l * 8);
        float d = bfu_lo(u.x) * bfu_lo(v.x) + bfu_hi(u.x) * bfu_hi(v.x)
                + bfu_lo(u.y) * bfu_lo(v.y) + bfu_hi(u.y) * bfu_hi(v.y)
                + bfu_lo(u.z) * bfu_lo(v.z) + bfu_hi(u.z) * bfu_hi(v.z)
                + bfu_lo(u.w) * bfu_lo(v.w) + bfu_hi(u.w) * bfu_hi(v.w);
        d += __shfl_xor(d, 1); d += __shfl_xor(d, 2);
        d += __shfl_xor(d, 4); d += __shfl_xor(d, 8);
        if (l == 0) out[e] = d;
    }
}

extern "C" void kernel_launch(void* const* d_in, const int* in_sizes, int n_in,
                              void* d_out, int out_size, void* d_ws, size_t ws_size,
                              hipStream_t stream)
{
    const float* x     = (const float*)d_in[0];
    const float* lin_w = (const float*)d_in[1];
    const float* lin_b = (const float*)d_in[2];
    const float* W1    = (const float*)d_in[3];
    const float* b1    = (const float*)d_in[4];
    const float* gamma = (const float*)d_in[5];
    const float* beta  = (const float*)d_in[6];
    const float* W2    = (const float*)d_in[7];
    const float* b2    = (const float*)d_in[8];
    const int*   ei    = (const int*)d_in[9];
    const int*   eli   = (const int*)d_in[10];
    float* out = (float*)d_out;

    const int N  = in_sizes[0] / 128;
    const int E  = in_sizes[9] / 2;
    const int EL = in_sizes[10] / 2;
    const size_t nd = (size_t)N * 128;
    const int nb = (N + 1023) / 1024;
    const int gemm_grid = (N + 63) / 64;

    // ws: A | B | hb | deg | rowptr | cur | bsum | col | wt_hi | wt_lo | part | ss
    float* A      = (float*)d_ws;
    float* B      = A + nd;
    unsigned short* hb = (unsigned short*)(B + nd);
    int*   deg    = (int*)(hb + nd);
    int*   rowptr = deg + N;
    int*   cur    = rowptr + N;
    int*   bsum   = cur + N;
    int*   col    = bsum + nb;
    unsigned short* wt_hi = (unsigned short*)(col + E);
    unsigned short* wt_lo = wt_hi + 7 * 16384;
    float* part   = (float*)(wt_lo + 7 * 16384);
    float* ss     = part + (size_t)256 * gemm_grid;

    const float invN = 1.0f / (float)N;

    // ---- weight prep + CSR build ----
    prep_w<<<448, 256, 0, stream>>>(lin_w, W1, W2, wt_hi, wt_lo);
    hipMemsetAsync(deg, 0, (size_t)N * sizeof(int), stream);
    hipMemsetAsync(cur, 0, (size_t)N * sizeof(int), stream);
    hist_deg<<<4096, 256, 0, stream>>>(ei + E, deg, E);
    scan_local<<<nb, 256, 0, stream>>>(deg, rowptr, bsum, N);
    scan_bsum<<<1, 64, 0, stream>>>(bsum, nb);
    fill_col<<<4096, 256, 0, stream>>>(ei, ei + E, rowptr, bsum, cur, col, E);

    // ---- h = x @ lin_w + lin_b  (fp32 + bf16 shadow) ----
    gemm_mfma<<<gemm_grid, 256, 0, stream>>>(x, nullptr, nullptr, nullptr, nullptr, nullptr,
                                             wt_hi, wt_lo, lin_b, ss, A, hb, part, N, 8);

    for (int l = 0; l < 3; l++) {
        const unsigned short* w1h = wt_hi + (size_t)(1 + l) * 16384;
        const unsigned short* w1l = wt_lo + (size_t)(1 + l) * 16384;
        const unsigned short* w2h = wt_hi + (size_t)(4 + l) * 16384;
        const unsigned short* w2l = wt_lo + (size_t)(4 + l) * 16384;
        // z = (h + agg) @ W1 + b1   (fused aggregation staging, BN partials)
        gemm_mfma<<<gemm_grid, 256, 0, stream>>>(A, hb, rowptr, bsum, deg, col,
                                                 w1h, w1l, b1 + (size_t)l * 128,
                                                 ss, B, hb, part, N, 4 | 32);
        bn_finalize<<<128, 256, 0, stream>>>(part, gemm_grid, invN,
                                             gamma + (size_t)l * 128,
                                             beta + (size_t)l * 128, ss);
        // h = relu(bn(z) @ W2 + b2) -> A fp32 (skipped on last layer) + hb
        const int f2 = 1 | 2 | 8 | (l == 2 ? 16 : 0);
        gemm_mfma<<<gemm_grid, 256, 0, stream>>>(B, nullptr, nullptr, nullptr, nullptr, nullptr,
                                                 w2h, w2l, b2 + (size_t)l * 128,
                                                 ss, A, hb, part, N, f2);
    }

    edge_dot<<<8192, 256, 0, stream>>>(hb, eli, eli + EL, out, EL);
}

// Round 6
// 675.760 us; speedup vs baseline: 12.9978x; 1.0995x over previous
//
#include <hip/hip_runtime.h>

// ===========================================================================
// GIN link-pred. R5->R6: CSR build replaced by chunk-bucketed counting sort.
// R5 counters: fill_col wrote 107 MB for 6.4 MB payload (every scattered 4B
// write = own 64B line writeback; cross-XCD lines never merge) at 0.9 TB/s.
// New build: (1) chunk_count per-block LDS hist of dst>>10; (2) chunk_scan
// -> per-(block,chunk) exclusive runs; (3) bucket_scatter packed
// (dstLow<<22|src) into runs (contiguous per block+chunk -> L2 merges);
// (4) chunk_place: one block per 1024-node chunk, LDS count+scan -> deg,
// absolute rowptr, col scatter confined to the block's 64 KB window.
// Removes hist_deg/scan_local/scan_bsum/fill_col/memsets.
// Requires N < 2^22 (src packed in 22 bits) and N <= 2^20 (nbc <= 1024).
// ===========================================================================

typedef __attribute__((ext_vector_type(8))) short short8v;
typedef __attribute__((ext_vector_type(4))) float float4v;

#define NBLK_SORT 512

__device__ __forceinline__ unsigned short f2bf(float f) {
    union { float f; unsigned u; } v; v.f = f;
    unsigned u = v.u;
    unsigned r = u + 0x7fffu + ((u >> 16) & 1u);   // RNE
    return (unsigned short)(r >> 16);
}
__device__ __forceinline__ float bf2f(unsigned short h) {
    union { unsigned u; float f; } v; v.u = ((unsigned)h) << 16;
    return v.f;
}
__device__ __forceinline__ float bfu_lo(unsigned u) {
    union { unsigned v; float f; } x; x.v = u << 16; return x.f;
}
__device__ __forceinline__ float bfu_hi(unsigned u) {
    union { unsigned v; float f; } x; x.v = u & 0xffff0000u; return x.f;
}

// ---------------------------------------------------------------------------
// Weight prep: 7 128x128 fp32 -> transposed (n-major) bf16 hi/lo splits.
// ---------------------------------------------------------------------------
__global__ __launch_bounds__(256) void prep_w(
    const float* __restrict__ lin_w, const float* __restrict__ W1,
    const float* __restrict__ W2,
    unsigned short* __restrict__ wt_hi, unsigned short* __restrict__ wt_lo)
{
    int idx = blockIdx.x * 256 + threadIdx.x;
    if (idx >= 7 * 16384) return;
    int m = idx >> 14;
    int r = idx & 16383;          // r = k*128 + n
    int k = r >> 7, n = r & 127;
    const float* src = (m == 0) ? lin_w
                     : (m <= 3) ? W1 + (size_t)(m - 1) * 16384
                                : W2 + (size_t)(m - 4) * 16384;
    float w = src[r];
    unsigned short hi = f2bf(w);
    unsigned short lo = f2bf(w - bf2f(hi));
    wt_hi[(size_t)m * 16384 + n * 128 + k] = hi;   // [n][k]
    wt_lo[(size_t)m * 16384 + n * 128 + k] = lo;
}

// ---------------------------------------------------------------------------
// Sort step 1: per-block histogram of dst>>10. cnt layout [chunk][block].
// ---------------------------------------------------------------------------
__global__ __launch_bounds__(256) void chunk_count(
    const int* __restrict__ dst, int* __restrict__ cnt, int E, int nbc)
{
    __shared__ int l[1024];
    const int tid = threadIdx.x, b = blockIdx.x;
    for (int i = tid; i < nbc; i += 256) l[i] = 0;
    __syncthreads();
    const int per = (E + gridDim.x - 1) / gridDim.x;
    const int e0 = b * per, e1 = min(E, e0 + per);
    for (int e = e0 + tid; e < e1; e += 256)
        atomicAdd(&l[dst[e] >> 10], 1);
    __syncthreads();
    for (int c = tid; c < nbc; c += 256) cnt[c * gridDim.x + b] = l[c];
}

// ---------------------------------------------------------------------------
// Sort step 2 (1 block): in-place per-chunk exclusive scan over blocks, then
// chunk-base scan folded in. cnt[c][b] becomes the absolute temp[] base for
// (block b, chunk c); chunkBase[c..nbc] = chunk region bounds.
// ---------------------------------------------------------------------------
__global__ __launch_bounds__(256) void chunk_scan(
    int* __restrict__ cnt, int* __restrict__ chunkBase, int nbc)
{
    __shared__ int ctot[1024];
    __shared__ int cbase[1025];
    const int t = threadIdx.x;
    for (int c = t; c < nbc; c += 256) {
        int base = 0;
        for (int b = 0; b < NBLK_SORT; b++) {
            int x = cnt[c * NBLK_SORT + b];
            cnt[c * NBLK_SORT + b] = base;
            base += x;
        }
        ctot[c] = base;
    }
    __syncthreads();
    if (t == 0) {
        int acc = 0;
        for (int c = 0; c < nbc; c++) { cbase[c] = acc; acc += ctot[c]; }
        cbase[nbc] = acc;
    }
    __syncthreads();
    for (int c = t; c < nbc; c += 256) {
        const int cb = cbase[c];
        for (int b = 0; b < NBLK_SORT; b++) cnt[c * NBLK_SORT + b] += cb;
        chunkBase[c] = cb;
    }
    if (t == 0) chunkBase[nbc] = cbase[nbc];
}

// ---------------------------------------------------------------------------
// Sort step 3: scatter packed (dstLow10<<22 | src) into per-(block,chunk)
// runs. Each block's writes to a chunk are consecutive -> L2 merges.
// ---------------------------------------------------------------------------
__global__ __launch_bounds__(256) void bucket_scatter(
    const int* __restrict__ src, const int* __restrict__ dst,
    const int* __restrict__ cnt, int* __restrict__ temp, int E, int nbc)
{
    __shared__ int lcur[1024];
    const int tid = threadIdx.x, b = blockIdx.x;
    for (int c = tid; c < nbc; c += 256) lcur[c] = cnt[c * gridDim.x + b];
    __syncthreads();
    const int per = (E + gridDim.x - 1) / gridDim.x;
    const int e0 = b * per, e1 = min(E, e0 + per);
    for (int e = e0 + tid; e < e1; e += 256) {
        const int d = dst[e];
        const int pos = atomicAdd(&lcur[d >> 10], 1);
        temp[pos] = ((d & 1023) << 22) | src[e];
    }
}

// ---------------------------------------------------------------------------
// Sort step 4: one block per chunk. LDS per-node count -> scan -> emit deg,
// absolute rowptr, and scatter col within the chunk's own region (64 KB
// window, single block/XCD -> writebacks fully merged).
// ---------------------------------------------------------------------------
__global__ __launch_bounds__(256) void chunk_place(
    const int* __restrict__ temp, const int* __restrict__ chunkBase,
    int* __restrict__ col, int* __restrict__ deg, int* __restrict__ rowptr,
    int N)
{
    __shared__ int lcnt[1024];
    __shared__ int lcur[1024];
    __shared__ int sh[256];
    const int tid = threadIdx.x, c = blockIdx.x;
    const int s = chunkBase[c], e2 = chunkBase[c + 1];

    for (int i = tid; i < 1024; i += 256) lcnt[i] = 0;
    __syncthreads();
    for (int i = s + tid; i < e2; i += 256)
        atomicAdd(&lcnt[((unsigned)temp[i]) >> 22], 1);
    __syncthreads();

    const int b4 = tid * 4;
    const int v0 = lcnt[b4], v1 = lcnt[b4 + 1], v2 = lcnt[b4 + 2], v3 = lcnt[b4 + 3];
    const int ts = v0 + v1 + v2 + v3;
    sh[tid] = ts;
    __syncthreads();
    for (int off = 1; off < 256; off <<= 1) {
        int x = (tid >= off) ? sh[tid - off] : 0;
        __syncthreads();
        sh[tid] += x;
        __syncthreads();
    }
    const int run = sh[tid] - ts;
    lcur[b4]     = s + run;
    lcur[b4 + 1] = s + run + v0;
    lcur[b4 + 2] = s + run + v0 + v1;
    lcur[b4 + 3] = s + run + v0 + v1 + v2;
    const int node0 = c << 10;
    if (node0 + b4 < N)     { deg[node0 + b4]     = v0; rowptr[node0 + b4]     = lcur[b4]; }
    if (node0 + b4 + 1 < N) { deg[node0 + b4 + 1] = v1; rowptr[node0 + b4 + 1] = lcur[b4 + 1]; }
    if (node0 + b4 + 2 < N) { deg[node0 + b4 + 2] = v2; rowptr[node0 + b4 + 2] = lcur[b4 + 2]; }
    if (node0 + b4 + 3 < N) { deg[node0 + b4 + 3] = v3; rowptr[node0 + b4 + 3] = lcur[b4 + 3]; }
    __syncthreads();

    for (int i = s + tid; i < e2; i += 256) {
        const unsigned p = (unsigned)temp[i];
        const int pos = atomicAdd(&lcur[p >> 22], 1);
        col[pos] = (int)(p & 0x3FFFFFu);
    }
}

// ---------------------------------------------------------------------------
// MFMA GEMM (+ optional fused neighbor aggregation in staging).
// out[N,128] = act(bn(stage(A))[N,128] @ W + bias), bf16x2 split (3 MFMA).
// flags: 1=BN apply+relu staging, 2=relu out, 4=BN stats partials,
//        8=bf16 shadow out, 16=skip fp32 out, 32=aggregate during staging.
// rowptr is ABSOLUTE (includes chunk base). In-place safe (out==A).
// ---------------------------------------------------------------------------
__global__ __launch_bounds__(256) void gemm_mfma(
    const float* __restrict__ Ain, const unsigned short* __restrict__ hbin,
    const int* __restrict__ rowptr, const int* __restrict__ deg,
    const int* __restrict__ col,
    const unsigned short* __restrict__ Wh, const unsigned short* __restrict__ Wl,
    const float* __restrict__ bias, const float* __restrict__ ss,
    float* __restrict__ outp, unsigned short* __restrict__ outb,
    float* __restrict__ part, int N, int flags)
{
    __shared__ __align__(16) unsigned short As[2][64][136];
    const int tid = threadIdx.x;
    const int row0 = blockIdx.x * 64;

    if (flags & 32) {
        // ---- staging with fused aggregation: 16 groups x 16 lanes ----
        const int g = tid >> 4;
        const int l = tid & 15;
        #pragma unroll
        for (int rr = 0; rr < 4; rr++) {
            const int r = g + rr * 16;
            const int row = row0 + r;
            float4 a0 = make_float4(0.f, 0.f, 0.f, 0.f);
            float4 a1 = make_float4(0.f, 0.f, 0.f, 0.f);
            if (row < N) {
                a0 = ((const float4*)(Ain + (size_t)row * 128))[l * 2];
                a1 = ((const float4*)(Ain + (size_t)row * 128))[l * 2 + 1];
                const int start = rowptr[row];
                const int cnt = deg[row];
                int j = 0;
                for (; j + 1 < cnt; j += 2) {
                    const int c0i = col[start + j];
                    const int c1i = col[start + j + 1];
                    const uint4 u0 = *(const uint4*)(hbin + (size_t)c0i * 128 + l * 8);
                    const uint4 u1 = *(const uint4*)(hbin + (size_t)c1i * 128 + l * 8);
                    a0.x += bfu_lo(u0.x); a0.y += bfu_hi(u0.x);
                    a0.z += bfu_lo(u0.y); a0.w += bfu_hi(u0.y);
                    a1.x += bfu_lo(u0.z); a1.y += bfu_hi(u0.z);
                    a1.z += bfu_lo(u0.w); a1.w += bfu_hi(u0.w);
                    a0.x += bfu_lo(u1.x); a0.y += bfu_hi(u1.x);
                    a0.z += bfu_lo(u1.y); a0.w += bfu_hi(u1.y);
                    a1.x += bfu_lo(u1.z); a1.y += bfu_hi(u1.z);
                    a1.z += bfu_lo(u1.w); a1.w += bfu_hi(u1.w);
                }
                if (j < cnt) {
                    const int c0i = col[start + j];
                    const uint4 u0 = *(const uint4*)(hbin + (size_t)c0i * 128 + l * 8);
                    a0.x += bfu_lo(u0.x); a0.y += bfu_hi(u0.x);
                    a0.z += bfu_lo(u0.y); a0.w += bfu_hi(u0.y);
                    a1.x += bfu_lo(u0.z); a1.y += bfu_hi(u0.z);
                    a1.z += bfu_lo(u0.w); a1.w += bfu_hi(u0.w);
                }
            }
            unsigned short h0 = f2bf(a0.x), h1 = f2bf(a0.y), h2 = f2bf(a0.z), h3 = f2bf(a0.w);
            unsigned short h4 = f2bf(a1.x), h5 = f2bf(a1.y), h6 = f2bf(a1.z), h7 = f2bf(a1.w);
            uint4 uh, ul;
            uh.x = (unsigned)h0 | ((unsigned)h1 << 16);
            uh.y = (unsigned)h2 | ((unsigned)h3 << 16);
            uh.z = (unsigned)h4 | ((unsigned)h5 << 16);
            uh.w = (unsigned)h6 | ((unsigned)h7 << 16);
            ul.x = (unsigned)f2bf(a0.x - bf2f(h0)) | ((unsigned)f2bf(a0.y - bf2f(h1)) << 16);
            ul.y = (unsigned)f2bf(a0.z - bf2f(h2)) | ((unsigned)f2bf(a0.w - bf2f(h3)) << 16);
            ul.z = (unsigned)f2bf(a1.x - bf2f(h4)) | ((unsigned)f2bf(a1.y - bf2f(h5)) << 16);
            ul.w = (unsigned)f2bf(a1.z - bf2f(h6)) | ((unsigned)f2bf(a1.w - bf2f(h7)) << 16);
            *(uint4*)&As[0][r][l * 8] = uh;
            *(uint4*)&As[1][r][l * 8] = ul;
        }
    } else {
        // ---- plain staging (optional BN apply + relu) ----
        for (int i = tid; i < 64 * 32; i += 256) {
            const int r = i >> 5, c4 = i & 31;
            const int row = row0 + r;
            float4 v = make_float4(0.f, 0.f, 0.f, 0.f);
            if (row < N) v = ((const float4*)(Ain + (size_t)row * 128))[c4];
            if (flags & 1) {
                const float4 sc = ((const float4*)ss)[c4];
                const float4 sh = ((const float4*)(ss + 128))[c4];
                v.x = fmaxf(v.x * sc.x + sh.x, 0.f);
                v.y = fmaxf(v.y * sc.y + sh.y, 0.f);
                v.z = fmaxf(v.z * sc.z + sh.z, 0.f);
                v.w = fmaxf(v.w * sc.w + sh.w, 0.f);
            }
            unsigned short h0 = f2bf(v.x), h1 = f2bf(v.y), h2 = f2bf(v.z), h3 = f2bf(v.w);
            unsigned short l0 = f2bf(v.x - bf2f(h0)), l1 = f2bf(v.y - bf2f(h1));
            unsigned short l2 = f2bf(v.z - bf2f(h2)), l3 = f2bf(v.w - bf2f(h3));
            uint2 uh, ul;
            uh.x = (unsigned)h0 | ((unsigned)h1 << 16);
            uh.y = (unsigned)h2 | ((unsigned)h3 << 16);
            ul.x = (unsigned)l0 | ((unsigned)l1 << 16);
            ul.y = (unsigned)l2 | ((unsigned)l3 << 16);
            *(uint2*)&As[0][r][c4 * 4] = uh;
            *(uint2*)&As[1][r][c4 * 4] = ul;
        }
    }
    __syncthreads();

    const int w    = tid >> 6;
    const int lane = tid & 63;
    const int ln   = lane & 15;
    const int lq   = lane >> 4;
    const int c0   = w * 32;

    float4v acc[4][2];
    #pragma unroll
    for (int nt = 0; nt < 2; nt++) {
        const float bv = bias[c0 + nt * 16 + ln];
        #pragma unroll
        for (int mt = 0; mt < 4; mt++) acc[mt][nt] = (float4v){bv, bv, bv, bv};
    }

    #pragma unroll
    for (int kc = 0; kc < 4; kc++) {
        const size_t b0 = (size_t)(c0 + ln) * 128 + kc * 32 + lq * 8;
        const size_t b1 = (size_t)(c0 + 16 + ln) * 128 + kc * 32 + lq * 8;
        const short8v bh0 = *(const short8v*)&Wh[b0];
        const short8v bl0 = *(const short8v*)&Wl[b0];
        const short8v bh1 = *(const short8v*)&Wh[b1];
        const short8v bl1 = *(const short8v*)&Wl[b1];
        #pragma unroll
        for (int mt = 0; mt < 4; mt++) {
            const short8v ah = *(const short8v*)&As[0][mt * 16 + ln][kc * 32 + lq * 8];
            const short8v al = *(const short8v*)&As[1][mt * 16 + ln][kc * 32 + lq * 8];
            acc[mt][0] = __builtin_amdgcn_mfma_f32_16x16x32_bf16(ah, bh0, acc[mt][0], 0, 0, 0);
            acc[mt][0] = __builtin_amdgcn_mfma_f32_16x16x32_bf16(ah, bl0, acc[mt][0], 0, 0, 0);
            acc[mt][0] = __builtin_amdgcn_mfma_f32_16x16x32_bf16(al, bh0, acc[mt][0], 0, 0, 0);
            acc[mt][1] = __builtin_amdgcn_mfma_f32_16x16x32_bf16(ah, bh1, acc[mt][1], 0, 0, 0);
            acc[mt][1] = __builtin_amdgcn_mfma_f32_16x16x32_bf16(ah, bl1, acc[mt][1], 0, 0, 0);
            acc[mt][1] = __builtin_amdgcn_mfma_f32_16x16x32_bf16(al, bh1, acc[mt][1], 0, 0, 0);
        }
    }

    // ---- store (C/D: col=lane&15, row=quad*4+reg) ----
    #pragma unroll
    for (int mt = 0; mt < 4; mt++) {
        #pragma unroll
        for (int nt = 0; nt < 2; nt++) {
            const int colv = c0 + nt * 16 + ln;
            #pragma unroll
            for (int i = 0; i < 4; i++) {
                const int row = row0 + mt * 16 + lq * 4 + i;
                if (row < N) {
                    float v = acc[mt][nt][i];
                    if (flags & 2) v = fmaxf(v, 0.f);
                    if (!(flags & 16)) outp[(size_t)row * 128 + colv] = v;
                    if (flags & 8) outb[(size_t)row * 128 + colv] = f2bf(v);
                }
            }
        }
    }

    // ---- BN stats partials (pre-activation z); wave owns its 32 cols ----
    if (flags & 4) {
        #pragma unroll
        for (int nt = 0; nt < 2; nt++) {
            float s = 0.f, q = 0.f;
            #pragma unroll
            for (int mt = 0; mt < 4; mt++) {
                #pragma unroll
                for (int i = 0; i < 4; i++) {
                    const int row = row0 + mt * 16 + lq * 4 + i;
                    if (row < N) { const float v = acc[mt][nt][i]; s += v; q += v * v; }
                }
            }
            s += __shfl_xor(s, 16); s += __shfl_xor(s, 32);
            q += __shfl_xor(q, 16); q += __shfl_xor(q, 32);
            if (lq == 0) {
                const int colv = c0 + nt * 16 + ln;
                part[(size_t)colv * gridDim.x + blockIdx.x] = s;
                part[(size_t)(128 + colv) * gridDim.x + blockIdx.x] = q;
            }
        }
    }
}

// ---------------------------------------------------------------------------
// BN finalize: reduce partials -> scale[c], shift[c]. grid=128 (1/channel).
// ---------------------------------------------------------------------------
__global__ __launch_bounds__(256) void bn_finalize(
    const float* __restrict__ part, int nblk, float invN,
    const float* __restrict__ gamma, const float* __restrict__ beta,
    float* __restrict__ ss)
{
    __shared__ float shs[256], shq[256];
    const int c = blockIdx.x, t = threadIdx.x;
    float s = 0.f, q = 0.f;
    for (int b = t; b < nblk; b += 256) {
        s += part[(size_t)c * nblk + b];
        q += part[(size_t)(128 + c) * nblk + b];
    }
    shs[t] = s; shq[t] = q;
    __syncthreads();
    for (int o = 128; o > 0; o >>= 1) {
        if (t < o) { shs[t] += shs[t + o]; shq[t] += shq[t + o]; }
        __syncthreads();
    }
    if (t == 0) {
        const float mu = shs[0] * invN;
        const float var = shq[0] * invN - mu * mu;
        const float sc = rsqrtf(fmaxf(var, 0.f) + 1e-5f) * gamma[c];
        ss[c] = sc;
        ss[128 + c] = beta[c] - mu * sc;
    }
}

// ---------------------------------------------------------------------------
// Classifier: out[e] = dot(hb[ia[e]], hb[ib[e]]), bf16 reads, fp32 math.
// ---------------------------------------------------------------------------
__global__ __launch_bounds__(256) void edge_dot(
    const unsigned short* __restrict__ hb, const int* __restrict__ ia,
    const int* __restrict__ ib, float* __restrict__ out, int EL)
{
    const int stride = gridDim.x * blockDim.x;
    const long long total = (long long)EL * 16;
    for (long long i = (long long)blockIdx.x * blockDim.x + threadIdx.x; i < total; i += stride) {
        const int e = (int)(i >> 4);
        const int l = (int)(i & 15);
        const int a = ia[e];
        const int b = ib[e];
        const uint4 u = *(const uint4*)(hb + (size_t)a * 128 + l * 8);
        const uint4 v = *(const uint4*)(hb + (size_t)b * 128 + l * 8);
        float d = bfu_lo(u.x) * bfu_lo(v.x) + bfu_hi(u.x) * bfu_hi(v.x)
                + bfu_lo(u.y) * bfu_lo(v.y) + bfu_hi(u.y) * bfu_hi(v.y)
                + bfu_lo(u.z) * bfu_lo(v.z) + bfu_hi(u.z) * bfu_hi(v.z)
                + bfu_lo(u.w) * bfu_lo(v.w) + bfu_hi(u.w) * bfu_hi(v.w);
        d += __shfl_xor(d, 1); d += __shfl_xor(d, 2);
        d += __shfl_xor(d, 4); d += __shfl_xor(d, 8);
        if (l == 0) out[e] = d;
    }
}

extern "C" void kernel_launch(void* const* d_in, const int* in_sizes, int n_in,
                              void* d_out, int out_size, void* d_ws, size_t ws_size,
                              hipStream_t stream)
{
    const float* x     = (const float*)d_in[0];
    const float* lin_w = (const float*)d_in[1];
    const float* lin_b = (const float*)d_in[2];
    const float* W1    = (const float*)d_in[3];
    const float* b1    = (const float*)d_in[4];
    const float* gamma = (const float*)d_in[5];
    const float* beta  = (const float*)d_in[6];
    const float* W2    = (const float*)d_in[7];
    const float* b2    = (const float*)d_in[8];
    const int*   ei    = (const int*)d_in[9];
    const int*   eli   = (const int*)d_in[10];
    float* out = (float*)d_out;

    const int N  = in_sizes[0] / 128;
    const int E  = in_sizes[9] / 2;
    const int EL = in_sizes[10] / 2;
    const size_t nd = (size_t)N * 128;
    const int nbc = (N + 1023) >> 10;            // 1024-node chunks
    const int gemm_grid = (N + 63) / 64;

    // ws: A | B | hb | deg | rowptr | cnt | chunkBase | temp | col | wts | part | ss
    float* A      = (float*)d_ws;
    float* B      = A + nd;
    unsigned short* hb = (unsigned short*)(B + nd);
    int*   deg    = (int*)(hb + nd);
    int*   rowptr = deg + N;
    int*   cnt    = rowptr + N;                  // [nbc][NBLK_SORT]
    int*   chunkBase = cnt + (size_t)nbc * NBLK_SORT;
    int*   temp   = chunkBase + nbc + 1;
    int*   col    = temp + E;
    unsigned short* wt_hi = (unsigned short*)(col + E);
    unsigned short* wt_lo = wt_hi + 7 * 16384;
    float* part   = (float*)(wt_lo + 7 * 16384);
    float* ss     = part + (size_t)256 * gemm_grid;

    const float invN = 1.0f / (float)N;

    // ---- weight prep + bucketed CSR build ----
    prep_w<<<448, 256, 0, stream>>>(lin_w, W1, W2, wt_hi, wt_lo);
    chunk_count<<<NBLK_SORT, 256, 0, stream>>>(ei + E, cnt, E, nbc);
    chunk_scan<<<1, 256, 0, stream>>>(cnt, chunkBase, nbc);
    bucket_scatter<<<NBLK_SORT, 256, 0, stream>>>(ei, ei + E, cnt, temp, E, nbc);
    chunk_place<<<nbc, 256, 0, stream>>>(temp, chunkBase, col, deg, rowptr, N);

    // ---- h = x @ lin_w + lin_b  (fp32 + bf16 shadow) ----
    gemm_mfma<<<gemm_grid, 256, 0, stream>>>(x, nullptr, nullptr, nullptr, nullptr,
                                             wt_hi, wt_lo, lin_b, ss, A, hb, part, N, 8);

    for (int l = 0; l < 3; l++) {
        const unsigned short* w1h = wt_hi + (size_t)(1 + l) * 16384;
        const unsigned short* w1l = wt_lo + (size_t)(1 + l) * 16384;
        const unsigned short* w2h = wt_hi + (size_t)(4 + l) * 16384;
        const unsigned short* w2l = wt_lo + (size_t)(4 + l) * 16384;
        // z = (h + agg) @ W1 + b1   (fused aggregation staging, BN partials)
        gemm_mfma<<<gemm_grid, 256, 0, stream>>>(A, hb, rowptr, deg, col,
                                                 w1h, w1l, b1 + (size_t)l * 128,
                                                 ss, B, hb, part, N, 4 | 32);
        bn_finalize<<<128, 256, 0, stream>>>(part, gemm_grid, invN,
                                             gamma + (size_t)l * 128,
                                             beta + (size_t)l * 128, ss);
        // h = relu(bn(z) @ W2 + b2) -> A fp32 (skipped on last layer) + hb
        const int f2 = 1 | 2 | 8 | (l == 2 ? 16 : 0);
        gemm_mfma<<<gemm_grid, 256, 0, stream>>>(B, nullptr, nullptr, nullptr, nullptr,
                                                 w2h, w2l, b2 + (size_t)l * 128,
                                                 ss, A, hb, part, N, f2);
    }

    edge_dot<<<8192, 256, 0, stream>>>(hb, eli, eli + EL, out, EL);
}

// Round 7
// 637.383 us; speedup vs baseline: 13.7804x; 1.0602x over previous
//
#include <hip/hip_runtime.h>

// ===========================================================================
// GIN link-pred. R6->R7: all activations flow through bf16 shadows; the fp32
// h/z streams are deleted. R6 counters: fused gather-GEMM = 104 us, FETCH
// 204 MB (gather), but lin/gemm2/gemm1 still streamed ~380 MB of fp32
// activations total. Now: gemm1 stages self+neighbors from hbH (bf16),
// writes z as bf16 hbZ; gemm2 stages hbZ + BN+relu, writes hbH. MFMA stays
// bf16x2 (A-sum of bf16 rows still carries sub-bf16 info; MfmaUtil was 3.6%).
// CSR via chunk-bucketed counting sort (R6). Requires N < 2^22.
// ===========================================================================

typedef __attribute__((ext_vector_type(8))) short short8v;
typedef __attribute__((ext_vector_type(4))) float float4v;

#define NBLK_SORT 512

__device__ __forceinline__ unsigned short f2bf(float f) {
    union { float f; unsigned u; } v; v.f = f;
    unsigned u = v.u;
    unsigned r = u + 0x7fffu + ((u >> 16) & 1u);   // RNE
    return (unsigned short)(r >> 16);
}
__device__ __forceinline__ float bf2f(unsigned short h) {
    union { unsigned u; float f; } v; v.u = ((unsigned)h) << 16;
    return v.f;
}
__device__ __forceinline__ float bfu_lo(unsigned u) {
    union { unsigned v; float f; } x; x.v = u << 16; return x.f;
}
__device__ __forceinline__ float bfu_hi(unsigned u) {
    union { unsigned v; float f; } x; x.v = u & 0xffff0000u; return x.f;
}

// ---------------------------------------------------------------------------
// Weight prep: 7 128x128 fp32 -> transposed (n-major) bf16 hi/lo splits.
// ---------------------------------------------------------------------------
__global__ __launch_bounds__(256) void prep_w(
    const float* __restrict__ lin_w, const float* __restrict__ W1,
    const float* __restrict__ W2,
    unsigned short* __restrict__ wt_hi, unsigned short* __restrict__ wt_lo)
{
    int idx = blockIdx.x * 256 + threadIdx.x;
    if (idx >= 7 * 16384) return;
    int m = idx >> 14;
    int r = idx & 16383;          // r = k*128 + n
    int k = r >> 7, n = r & 127;
    const float* src = (m == 0) ? lin_w
                     : (m <= 3) ? W1 + (size_t)(m - 1) * 16384
                                : W2 + (size_t)(m - 4) * 16384;
    float w = src[r];
    unsigned short hi = f2bf(w);
    unsigned short lo = f2bf(w - bf2f(hi));
    wt_hi[(size_t)m * 16384 + n * 128 + k] = hi;   // [n][k]
    wt_lo[(size_t)m * 16384 + n * 128 + k] = lo;
}

// ---------------------------------------------------------------------------
// Bucketed counting sort -> CSR (chunk = 1024 dst nodes). See header.
// ---------------------------------------------------------------------------
__global__ __launch_bounds__(256) void chunk_count(
    const int* __restrict__ dst, int* __restrict__ cnt, int E, int nbc)
{
    __shared__ int l[1024];
    const int tid = threadIdx.x, b = blockIdx.x;
    for (int i = tid; i < nbc; i += 256) l[i] = 0;
    __syncthreads();
    const int per = (E + gridDim.x - 1) / gridDim.x;
    const int e0 = b * per, e1 = min(E, e0 + per);
    for (int e = e0 + tid; e < e1; e += 256)
        atomicAdd(&l[dst[e] >> 10], 1);
    __syncthreads();
    for (int c = tid; c < nbc; c += 256) cnt[c * gridDim.x + b] = l[c];
}

__global__ __launch_bounds__(256) void chunk_scan(
    int* __restrict__ cnt, int* __restrict__ chunkBase, int nbc)
{
    __shared__ int ctot[1024];
    __shared__ int cbase[1025];
    const int t = threadIdx.x;
    for (int c = t; c < nbc; c += 256) {
        int base = 0;
        for (int b = 0; b < NBLK_SORT; b++) {
            int x = cnt[c * NBLK_SORT + b];
            cnt[c * NBLK_SORT + b] = base;
            base += x;
        }
        ctot[c] = base;
    }
    __syncthreads();
    if (t == 0) {
        int acc = 0;
        for (int c = 0; c < nbc; c++) { cbase[c] = acc; acc += ctot[c]; }
        cbase[nbc] = acc;
    }
    __syncthreads();
    for (int c = t; c < nbc; c += 256) {
        const int cb = cbase[c];
        for (int b = 0; b < NBLK_SORT; b++) cnt[c * NBLK_SORT + b] += cb;
        chunkBase[c] = cb;
    }
    if (t == 0) chunkBase[nbc] = cbase[nbc];
}

__global__ __launch_bounds__(256) void bucket_scatter(
    const int* __restrict__ src, const int* __restrict__ dst,
    const int* __restrict__ cnt, int* __restrict__ temp, int E, int nbc)
{
    __shared__ int lcur[1024];
    const int tid = threadIdx.x, b = blockIdx.x;
    for (int c = tid; c < nbc; c += 256) lcur[c] = cnt[c * gridDim.x + b];
    __syncthreads();
    const int per = (E + gridDim.x - 1) / gridDim.x;
    const int e0 = b * per, e1 = min(E, e0 + per);
    for (int e = e0 + tid; e < e1; e += 256) {
        const int d = dst[e];
        const int pos = atomicAdd(&lcur[d >> 10], 1);
        temp[pos] = ((d & 1023) << 22) | src[e];
    }
}

__global__ __launch_bounds__(256) void chunk_place(
    const int* __restrict__ temp, const int* __restrict__ chunkBase,
    int* __restrict__ col, int* __restrict__ deg, int* __restrict__ rowptr,
    int N)
{
    __shared__ int lcnt[1024];
    __shared__ int lcur[1024];
    __shared__ int sh[256];
    const int tid = threadIdx.x, c = blockIdx.x;
    const int s = chunkBase[c], e2 = chunkBase[c + 1];

    for (int i = tid; i < 1024; i += 256) lcnt[i] = 0;
    __syncthreads();
    for (int i = s + tid; i < e2; i += 256)
        atomicAdd(&lcnt[((unsigned)temp[i]) >> 22], 1);
    __syncthreads();

    const int b4 = tid * 4;
    const int v0 = lcnt[b4], v1 = lcnt[b4 + 1], v2 = lcnt[b4 + 2], v3 = lcnt[b4 + 3];
    const int ts = v0 + v1 + v2 + v3;
    sh[tid] = ts;
    __syncthreads();
    for (int off = 1; off < 256; off <<= 1) {
        int x = (tid >= off) ? sh[tid - off] : 0;
        __syncthreads();
        sh[tid] += x;
        __syncthreads();
    }
    const int run = sh[tid] - ts;
    lcur[b4]     = s + run;
    lcur[b4 + 1] = s + run + v0;
    lcur[b4 + 2] = s + run + v0 + v1;
    lcur[b4 + 3] = s + run + v0 + v1 + v2;
    const int node0 = c << 10;
    if (node0 + b4 < N)     { deg[node0 + b4]     = v0; rowptr[node0 + b4]     = lcur[b4]; }
    if (node0 + b4 + 1 < N) { deg[node0 + b4 + 1] = v1; rowptr[node0 + b4 + 1] = lcur[b4 + 1]; }
    if (node0 + b4 + 2 < N) { deg[node0 + b4 + 2] = v2; rowptr[node0 + b4 + 2] = lcur[b4 + 2]; }
    if (node0 + b4 + 3 < N) { deg[node0 + b4 + 3] = v3; rowptr[node0 + b4 + 3] = lcur[b4 + 3]; }
    __syncthreads();

    for (int i = s + tid; i < e2; i += 256) {
        const unsigned p = (unsigned)temp[i];
        const int pos = atomicAdd(&lcur[p >> 22], 1);
        col[pos] = (int)(p & 0x3FFFFFu);
    }
}

// ---------------------------------------------------------------------------
// MFMA GEMM, bf16 in / bf16 out. outb[N,128] = act(bn(stage(in)) @ W + bias).
// flags: 1=BN apply+relu on staged input, 2=relu on output,
//        4=emit BN stats partials (pre-activation z),
//        32=staging aggregates self+neighbors from AinB via CSR,
//        64=input is bf16 (AinB), else fp32 (Ain32 -- lin layer only).
// Block 256 thr = 4 waves, tile 64x128; wave w -> cols w*32..+31 (acc[4][2]).
// LDS A tile bf16 hi/lo, stride 136.
// ---------------------------------------------------------------------------
__global__ __launch_bounds__(256) void gemm_mfma(
    const float* __restrict__ Ain32, const unsigned short* __restrict__ AinB,
    const int* __restrict__ rowptr, const int* __restrict__ deg,
    const int* __restrict__ col,
    const unsigned short* __restrict__ Wh, const unsigned short* __restrict__ Wl,
    const float* __restrict__ bias, const float* __restrict__ ss,
    unsigned short* __restrict__ outb, float* __restrict__ part,
    int N, int flags)
{
    __shared__ __align__(16) unsigned short As[2][64][136];
    const int tid = threadIdx.x;
    const int row0 = blockIdx.x * 64;

    if (flags & 32) {
        // ---- staging with fused aggregation: 16 groups x 16 lanes ----
        const int g = tid >> 4;
        const int l = tid & 15;
        #pragma unroll
        for (int rr = 0; rr < 4; rr++) {
            const int r = g + rr * 16;
            const int row = row0 + r;
            float4 a0 = make_float4(0.f, 0.f, 0.f, 0.f);
            float4 a1 = make_float4(0.f, 0.f, 0.f, 0.f);
            if (row < N) {
                const uint4 su = *(const uint4*)(AinB + (size_t)row * 128 + l * 8);
                a0.x = bfu_lo(su.x); a0.y = bfu_hi(su.x);
                a0.z = bfu_lo(su.y); a0.w = bfu_hi(su.y);
                a1.x = bfu_lo(su.z); a1.y = bfu_hi(su.z);
                a1.z = bfu_lo(su.w); a1.w = bfu_hi(su.w);
                const int start = rowptr[row];
                const int cnt = deg[row];
                int j = 0;
                for (; j + 1 < cnt; j += 2) {
                    const int c0i = col[start + j];
                    const int c1i = col[start + j + 1];
                    const uint4 u0 = *(const uint4*)(AinB + (size_t)c0i * 128 + l * 8);
                    const uint4 u1 = *(const uint4*)(AinB + (size_t)c1i * 128 + l * 8);
                    a0.x += bfu_lo(u0.x); a0.y += bfu_hi(u0.x);
                    a0.z += bfu_lo(u0.y); a0.w += bfu_hi(u0.y);
                    a1.x += bfu_lo(u0.z); a1.y += bfu_hi(u0.z);
                    a1.z += bfu_lo(u0.w); a1.w += bfu_hi(u0.w);
                    a0.x += bfu_lo(u1.x); a0.y += bfu_hi(u1.x);
                    a0.z += bfu_lo(u1.y); a0.w += bfu_hi(u1.y);
                    a1.x += bfu_lo(u1.z); a1.y += bfu_hi(u1.z);
                    a1.z += bfu_lo(u1.w); a1.w += bfu_hi(u1.w);
                }
                if (j < cnt) {
                    const int c0i = col[start + j];
                    const uint4 u0 = *(const uint4*)(AinB + (size_t)c0i * 128 + l * 8);
                    a0.x += bfu_lo(u0.x); a0.y += bfu_hi(u0.x);
                    a0.z += bfu_lo(u0.y); a0.w += bfu_hi(u0.y);
                    a1.x += bfu_lo(u0.z); a1.y += bfu_hi(u0.z);
                    a1.z += bfu_lo(u0.w); a1.w += bfu_hi(u0.w);
                }
            }
            unsigned short h0 = f2bf(a0.x), h1 = f2bf(a0.y), h2 = f2bf(a0.z), h3 = f2bf(a0.w);
            unsigned short h4 = f2bf(a1.x), h5 = f2bf(a1.y), h6 = f2bf(a1.z), h7 = f2bf(a1.w);
            uint4 uh, ul;
            uh.x = (unsigned)h0 | ((unsigned)h1 << 16);
            uh.y = (unsigned)h2 | ((unsigned)h3 << 16);
            uh.z = (unsigned)h4 | ((unsigned)h5 << 16);
            uh.w = (unsigned)h6 | ((unsigned)h7 << 16);
            ul.x = (unsigned)f2bf(a0.x - bf2f(h0)) | ((unsigned)f2bf(a0.y - bf2f(h1)) << 16);
            ul.y = (unsigned)f2bf(a0.z - bf2f(h2)) | ((unsigned)f2bf(a0.w - bf2f(h3)) << 16);
            ul.z = (unsigned)f2bf(a1.x - bf2f(h4)) | ((unsigned)f2bf(a1.y - bf2f(h5)) << 16);
            ul.w = (unsigned)f2bf(a1.z - bf2f(h6)) | ((unsigned)f2bf(a1.w - bf2f(h7)) << 16);
            *(uint4*)&As[0][r][l * 8] = uh;
            *(uint4*)&As[1][r][l * 8] = ul;
        }
    } else if (flags & 64) {
        // ---- bf16 staging (optional BN apply + relu): 64 rows x 16 groups ----
        for (int i = tid; i < 64 * 16; i += 256) {
            const int r = i >> 4, c8 = i & 15;
            const int row = row0 + r;
            float4 v0 = make_float4(0.f, 0.f, 0.f, 0.f);
            float4 v1 = make_float4(0.f, 0.f, 0.f, 0.f);
            if (row < N) {
                const uint4 u = *(const uint4*)(AinB + (size_t)row * 128 + c8 * 8);
                v0.x = bfu_lo(u.x); v0.y = bfu_hi(u.x);
                v0.z = bfu_lo(u.y); v0.w = bfu_hi(u.y);
                v1.x = bfu_lo(u.z); v1.y = bfu_hi(u.z);
                v1.z = bfu_lo(u.w); v1.w = bfu_hi(u.w);
            }
            if (flags & 1) {
                const float4 sc0 = ((const float4*)ss)[c8 * 2];
                const float4 sc1 = ((const float4*)ss)[c8 * 2 + 1];
                const float4 sh0 = ((const float4*)(ss + 128))[c8 * 2];
                const float4 sh1 = ((const float4*)(ss + 128))[c8 * 2 + 1];
                v0.x = fmaxf(v0.x * sc0.x + sh0.x, 0.f);
                v0.y = fmaxf(v0.y * sc0.y + sh0.y, 0.f);
                v0.z = fmaxf(v0.z * sc0.z + sh0.z, 0.f);
                v0.w = fmaxf(v0.w * sc0.w + sh0.w, 0.f);
                v1.x = fmaxf(v1.x * sc1.x + sh1.x, 0.f);
                v1.y = fmaxf(v1.y * sc1.y + sh1.y, 0.f);
                v1.z = fmaxf(v1.z * sc1.z + sh1.z, 0.f);
                v1.w = fmaxf(v1.w * sc1.w + sh1.w, 0.f);
            }
            unsigned short h0 = f2bf(v0.x), h1 = f2bf(v0.y), h2 = f2bf(v0.z), h3 = f2bf(v0.w);
            unsigned short h4 = f2bf(v1.x), h5 = f2bf(v1.y), h6 = f2bf(v1.z), h7 = f2bf(v1.w);
            uint4 uh, ul;
            uh.x = (unsigned)h0 | ((unsigned)h1 << 16);
            uh.y = (unsigned)h2 | ((unsigned)h3 << 16);
            uh.z = (unsigned)h4 | ((unsigned)h5 << 16);
            uh.w = (unsigned)h6 | ((unsigned)h7 << 16);
            ul.x = (unsigned)f2bf(v0.x - bf2f(h0)) | ((unsigned)f2bf(v0.y - bf2f(h1)) << 16);
            ul.y = (unsigned)f2bf(v0.z - bf2f(h2)) | ((unsigned)f2bf(v0.w - bf2f(h3)) << 16);
            ul.z = (unsigned)f2bf(v1.x - bf2f(h4)) | ((unsigned)f2bf(v1.y - bf2f(h5)) << 16);
            ul.w = (unsigned)f2bf(v1.z - bf2f(h6)) | ((unsigned)f2bf(v1.w - bf2f(h7)) << 16);
            *(uint4*)&As[0][r][c8 * 8] = uh;
            *(uint4*)&As[1][r][c8 * 8] = ul;
        }
    } else {
        // ---- fp32 staging (lin layer: x input) ----
        for (int i = tid; i < 64 * 32; i += 256) {
            const int r = i >> 5, c4 = i & 31;
            const int row = row0 + r;
            float4 v = make_float4(0.f, 0.f, 0.f, 0.f);
            if (row < N) v = ((const float4*)(Ain32 + (size_t)row * 128))[c4];
            unsigned short h0 = f2bf(v.x), h1 = f2bf(v.y), h2 = f2bf(v.z), h3 = f2bf(v.w);
            unsigned short l0 = f2bf(v.x - bf2f(h0)), l1 = f2bf(v.y - bf2f(h1));
            unsigned short l2 = f2bf(v.z - bf2f(h2)), l3 = f2bf(v.w - bf2f(h3));
            uint2 uh, ul;
            uh.x = (unsigned)h0 | ((unsigned)h1 << 16);
            uh.y = (unsigned)h2 | ((unsigned)h3 << 16);
            ul.x = (unsigned)l0 | ((unsigned)l1 << 16);
            ul.y = (unsigned)l2 | ((unsigned)l3 << 16);
            *(uint2*)&As[0][r][c4 * 4] = uh;
            *(uint2*)&As[1][r][c4 * 4] = ul;
        }
    }
    __syncthreads();

    const int w    = tid >> 6;
    const int lane = tid & 63;
    const int ln   = lane & 15;
    const int lq   = lane >> 4;
    const int c0   = w * 32;

    float4v acc[4][2];
    #pragma unroll
    for (int nt = 0; nt < 2; nt++) {
        const float bv = bias[c0 + nt * 16 + ln];
        #pragma unroll
        for (int mt = 0; mt < 4; mt++) acc[mt][nt] = (float4v){bv, bv, bv, bv};
    }

    #pragma unroll
    for (int kc = 0; kc < 4; kc++) {
        const size_t b0 = (size_t)(c0 + ln) * 128 + kc * 32 + lq * 8;
        const size_t b1 = (size_t)(c0 + 16 + ln) * 128 + kc * 32 + lq * 8;
        const short8v bh0 = *(const short8v*)&Wh[b0];
        const short8v bl0 = *(const short8v*)&Wl[b0];
        const short8v bh1 = *(const short8v*)&Wh[b1];
        const short8v bl1 = *(const short8v*)&Wl[b1];
        #pragma unroll
        for (int mt = 0; mt < 4; mt++) {
            const short8v ah = *(const short8v*)&As[0][mt * 16 + ln][kc * 32 + lq * 8];
            const short8v al = *(const short8v*)&As[1][mt * 16 + ln][kc * 32 + lq * 8];
            acc[mt][0] = __builtin_amdgcn_mfma_f32_16x16x32_bf16(ah, bh0, acc[mt][0], 0, 0, 0);
            acc[mt][0] = __builtin_amdgcn_mfma_f32_16x16x32_bf16(ah, bl0, acc[mt][0], 0, 0, 0);
            acc[mt][0] = __builtin_amdgcn_mfma_f32_16x16x32_bf16(al, bh0, acc[mt][0], 0, 0, 0);
            acc[mt][1] = __builtin_amdgcn_mfma_f32_16x16x32_bf16(ah, bh1, acc[mt][1], 0, 0, 0);
            acc[mt][1] = __builtin_amdgcn_mfma_f32_16x16x32_bf16(ah, bl1, acc[mt][1], 0, 0, 0);
            acc[mt][1] = __builtin_amdgcn_mfma_f32_16x16x32_bf16(al, bh1, acc[mt][1], 0, 0, 0);
        }
    }

    // ---- store bf16 (C/D: col=lane&15, row=quad*4+reg) ----
    #pragma unroll
    for (int mt = 0; mt < 4; mt++) {
        #pragma unroll
        for (int nt = 0; nt < 2; nt++) {
            const int colv = c0 + nt * 16 + ln;
            #pragma unroll
            for (int i = 0; i < 4; i++) {
                const int row = row0 + mt * 16 + lq * 4 + i;
                if (row < N) {
                    float v = acc[mt][nt][i];
                    if (flags & 2) v = fmaxf(v, 0.f);
                    outb[(size_t)row * 128 + colv] = f2bf(v);
                }
            }
        }
    }

    // ---- BN stats partials (pre-activation z); wave owns its 32 cols ----
    if (flags & 4) {
        #pragma unroll
        for (int nt = 0; nt < 2; nt++) {
            float s = 0.f, q = 0.f;
            #pragma unroll
            for (int mt = 0; mt < 4; mt++) {
                #pragma unroll
                for (int i = 0; i < 4; i++) {
                    const int row = row0 + mt * 16 + lq * 4 + i;
                    if (row < N) { const float v = acc[mt][nt][i]; s += v; q += v * v; }
                }
            }
            s += __shfl_xor(s, 16); s += __shfl_xor(s, 32);
            q += __shfl_xor(q, 16); q += __shfl_xor(q, 32);
            if (lq == 0) {
                const int colv = c0 + nt * 16 + ln;
                part[(size_t)colv * gridDim.x + blockIdx.x] = s;
                part[(size_t)(128 + colv) * gridDim.x + blockIdx.x] = q;
            }
        }
    }
}

// ---------------------------------------------------------------------------
// BN finalize: reduce partials -> scale[c], shift[c]. grid=128 (1/channel).
// NOTE: stats from fp32 acc; applied later to bf16-rounded z (same values
// up to one rounding -- acceptable, model is value-compared not semantics).
// ---------------------------------------------------------------------------
__global__ __launch_bounds__(256) void bn_finalize(
    const float* __restrict__ part, int nblk, float invN,
    const float* __restrict__ gamma, const float* __restrict__ beta,
    float* __restrict__ ss)
{
    __shared__ float shs[256], shq[256];
    const int c = blockIdx.x, t = threadIdx.x;
    float s = 0.f, q = 0.f;
    for (int b = t; b < nblk; b += 256) {
        s += part[(size_t)c * nblk + b];
        q += part[(size_t)(128 + c) * nblk + b];
    }
    shs[t] = s; shq[t] = q;
    __syncthreads();
    for (int o = 128; o > 0; o >>= 1) {
        if (t < o) { shs[t] += shs[t + o]; shq[t] += shq[t + o]; }
        __syncthreads();
    }
    if (t == 0) {
        const float mu = shs[0] * invN;
        const float var = shq[0] * invN - mu * mu;
        const float sc = rsqrtf(fmaxf(var, 0.f) + 1e-5f) * gamma[c];
        ss[c] = sc;
        ss[128 + c] = beta[c] - mu * sc;
    }
}

// ---------------------------------------------------------------------------
// Classifier: out[e] = dot(hb[ia[e]], hb[ib[e]]), bf16 reads, fp32 math.
// ---------------------------------------------------------------------------
__global__ __launch_bounds__(256) void edge_dot(
    const unsigned short* __restrict__ hb, const int* __restrict__ ia,
    const int* __restrict__ ib, float* __restrict__ out, int EL)
{
    const int stride = gridDim.x * blockDim.x;
    const long long total = (long long)EL * 16;
    for (long long i = (long long)blockIdx.x * blockDim.x + threadIdx.x; i < total; i += stride) {
        const int e = (int)(i >> 4);
        const int l = (int)(i & 15);
        const int a = ia[e];
        const int b = ib[e];
        const uint4 u = *(const uint4*)(hb + (size_t)a * 128 + l * 8);
        const uint4 v = *(const uint4*)(hb + (size_t)b * 128 + l * 8);
        float d = bfu_lo(u.x) * bfu_lo(v.x) + bfu_hi(u.x) * bfu_hi(v.x)
                + bfu_lo(u.y) * bfu_lo(v.y) + bfu_hi(u.y) * bfu_hi(v.y)
                + bfu_lo(u.z) * bfu_lo(v.z) + bfu_hi(u.z) * bfu_hi(v.z)
                + bfu_lo(u.w) * bfu_lo(v.w) + bfu_hi(u.w) * bfu_hi(v.w);
        d += __shfl_xor(d, 1); d += __shfl_xor(d, 2);
        d += __shfl_xor(d, 4); d += __shfl_xor(d, 8);
        if (l == 0) out[e] = d;
    }
}

extern "C" void kernel_launch(void* const* d_in, const int* in_sizes, int n_in,
                              void* d_out, int out_size, void* d_ws, size_t ws_size,
                              hipStream_t stream)
{
    const float* x     = (const float*)d_in[0];
    const float* lin_w = (const float*)d_in[1];
    const float* lin_b = (const float*)d_in[2];
    const float* W1    = (const float*)d_in[3];
    const float* b1    = (const float*)d_in[4];
    const float* gamma = (const float*)d_in[5];
    const float* beta  = (const float*)d_in[6];
    const float* W2    = (const float*)d_in[7];
    const float* b2    = (const float*)d_in[8];
    const int*   ei    = (const int*)d_in[9];
    const int*   eli   = (const int*)d_in[10];
    float* out = (float*)d_out;

    const int N  = in_sizes[0] / 128;
    const int E  = in_sizes[9] / 2;
    const int EL = in_sizes[10] / 2;
    const size_t nd = (size_t)N * 128;
    const int nbc = (N + 1023) >> 10;            // 1024-node chunks
    const int gemm_grid = (N + 63) / 64;

    // ws: hbH | hbZ | deg | rowptr | cnt | chunkBase | temp | col | wts | part | ss
    unsigned short* hbH = (unsigned short*)d_ws;
    unsigned short* hbZ = hbH + nd;
    int*   deg    = (int*)(hbZ + nd);
    int*   rowptr = deg + N;
    int*   cnt    = rowptr + N;                  // [nbc][NBLK_SORT]
    int*   chunkBase = cnt + (size_t)nbc * NBLK_SORT;
    int*   temp   = chunkBase + nbc + 1;
    int*   col    = temp + E;
    unsigned short* wt_hi = (unsigned short*)(col + E);
    unsigned short* wt_lo = wt_hi + 7 * 16384;
    float* part   = (float*)(wt_lo + 7 * 16384);
    float* ss     = part + (size_t)256 * gemm_grid;

    const float invN = 1.0f / (float)N;

    // ---- weight prep + bucketed CSR build ----
    prep_w<<<448, 256, 0, stream>>>(lin_w, W1, W2, wt_hi, wt_lo);
    chunk_count<<<NBLK_SORT, 256, 0, stream>>>(ei + E, cnt, E, nbc);
    chunk_scan<<<1, 256, 0, stream>>>(cnt, chunkBase, nbc);
    bucket_scatter<<<NBLK_SORT, 256, 0, stream>>>(ei, ei + E, cnt, temp, E, nbc);
    chunk_place<<<nbc, 256, 0, stream>>>(temp, chunkBase, col, deg, rowptr, N);

    // ---- h = x @ lin_w + lin_b  -> hbH (bf16) ----
    gemm_mfma<<<gemm_grid, 256, 0, stream>>>(x, nullptr, nullptr, nullptr, nullptr,
                                             wt_hi, wt_lo, lin_b, ss, hbH, part, N, 0);

    for (int l = 0; l < 3; l++) {
        const unsigned short* w1h = wt_hi + (size_t)(1 + l) * 16384;
        const unsigned short* w1l = wt_lo + (size_t)(1 + l) * 16384;
        const unsigned short* w2h = wt_hi + (size_t)(4 + l) * 16384;
        const unsigned short* w2l = wt_lo + (size_t)(4 + l) * 16384;
        // z = (h + agg) @ W1 + b1 : gather from hbH, write hbZ, BN partials
        gemm_mfma<<<gemm_grid, 256, 0, stream>>>(nullptr, hbH, rowptr, deg, col,
                                                 w1h, w1l, b1 + (size_t)l * 128,
                                                 ss, hbZ, part, N, 4 | 32 | 64);
        bn_finalize<<<128, 256, 0, stream>>>(part, gemm_grid, invN,
                                             gamma + (size_t)l * 128,
                                             beta + (size_t)l * 128, ss);
        // h = relu(bn(z) @ W2 + b2) : stage hbZ + BN + relu, write hbH
        gemm_mfma<<<gemm_grid, 256, 0, stream>>>(nullptr, hbZ, nullptr, nullptr, nullptr,
                                                 w2h, w2l, b2 + (size_t)l * 128,
                                                 ss, hbH, part, N, 1 | 2 | 64);
    }

    edge_dot<<<8192, 256, 0, stream>>>(hbH, eli, eli + EL, out, EL);
}

// Round 8
// 627.829 us; speedup vs baseline: 13.9901x; 1.0152x over previous
//
#include <hip/hip_runtime.h>
#include <hip/hip_bf16.h>

// ===========================================================================
// GIN link-pred. R7->R8: A-side lo-term dropped (A operands are already
// bf16-derived; W keeps hi/lo). R7 evidence: gather-GEMM latency-bound
// (FETCH fell 204->187 MB but dur stuck at 100 us; VALUBusy 23%, Occ 31%),
// gemm2/lin VALU-bound on hi/lo staging (~45 us for 51 MB I/O).
// Changes: single-bf16 A staging via v_cvt_pk_bf16_f32, LDS 34->17 KB
// (4 -> 8 blocks/CU => ~2x latency hiding for the fused gather).
// CSR via chunk-bucketed counting sort (R6). Requires N < 2^22.
// ===========================================================================

typedef __attribute__((ext_vector_type(8))) short short8v;
typedef __attribute__((ext_vector_type(4))) float float4v;

#define NBLK_SORT 512

__device__ __forceinline__ unsigned short f2bf(float f) {
    union { float f; unsigned u; } v; v.f = f;
    unsigned u = v.u;
    unsigned r = u + 0x7fffu + ((u >> 16) & 1u);   // RNE
    return (unsigned short)(r >> 16);
}
__device__ __forceinline__ float bf2f(unsigned short h) {
    union { unsigned u; float f; } v; v.u = ((unsigned)h) << 16;
    return v.f;
}
__device__ __forceinline__ float bfu_lo(unsigned u) {
    union { unsigned v; float f; } x; x.v = u << 16; return x.f;
}
__device__ __forceinline__ float bfu_hi(unsigned u) {
    union { unsigned v; float f; } x; x.v = u & 0xffff0000u; return x.f;
}
// packed RNE f32x2 -> bf16x2 (lowers to v_cvt_pk_bf16_f32 on gfx950)
__device__ __forceinline__ unsigned pkbf(float x, float y) {
    __hip_bfloat162 t = __float22bfloat162_rn(float2{x, y});
    union { __hip_bfloat162 b; unsigned u; } c; c.b = t;
    return c.u;
}

// ---------------------------------------------------------------------------
// Weight prep: 7 128x128 fp32 -> transposed (n-major) bf16 hi/lo splits.
// ---------------------------------------------------------------------------
__global__ __launch_bounds__(256) void prep_w(
    const float* __restrict__ lin_w, const float* __restrict__ W1,
    const float* __restrict__ W2,
    unsigned short* __restrict__ wt_hi, unsigned short* __restrict__ wt_lo)
{
    int idx = blockIdx.x * 256 + threadIdx.x;
    if (idx >= 7 * 16384) return;
    int m = idx >> 14;
    int r = idx & 16383;          // r = k*128 + n
    int k = r >> 7, n = r & 127;
    const float* src = (m == 0) ? lin_w
                     : (m <= 3) ? W1 + (size_t)(m - 1) * 16384
                                : W2 + (size_t)(m - 4) * 16384;
    float w = src[r];
    unsigned short hi = f2bf(w);
    unsigned short lo = f2bf(w - bf2f(hi));
    wt_hi[(size_t)m * 16384 + n * 128 + k] = hi;   // [n][k]
    wt_lo[(size_t)m * 16384 + n * 128 + k] = lo;
}

// ---------------------------------------------------------------------------
// Bucketed counting sort -> CSR (chunk = 1024 dst nodes).
// ---------------------------------------------------------------------------
__global__ __launch_bounds__(256) void chunk_count(
    const int* __restrict__ dst, int* __restrict__ cnt, int E, int nbc)
{
    __shared__ int l[1024];
    const int tid = threadIdx.x, b = blockIdx.x;
    for (int i = tid; i < nbc; i += 256) l[i] = 0;
    __syncthreads();
    const int per = (E + gridDim.x - 1) / gridDim.x;
    const int e0 = b * per, e1 = min(E, e0 + per);
    for (int e = e0 + tid; e < e1; e += 256)
        atomicAdd(&l[dst[e] >> 10], 1);
    __syncthreads();
    for (int c = tid; c < nbc; c += 256) cnt[c * gridDim.x + b] = l[c];
}

__global__ __launch_bounds__(256) void chunk_scan(
    int* __restrict__ cnt, int* __restrict__ chunkBase, int nbc)
{
    __shared__ int ctot[1024];
    __shared__ int cbase[1025];
    const int t = threadIdx.x;
    for (int c = t; c < nbc; c += 256) {
        int base = 0;
        for (int b = 0; b < NBLK_SORT; b++) {
            int x = cnt[c * NBLK_SORT + b];
            cnt[c * NBLK_SORT + b] = base;
            base += x;
        }
        ctot[c] = base;
    }
    __syncthreads();
    if (t == 0) {
        int acc = 0;
        for (int c = 0; c < nbc; c++) { cbase[c] = acc; acc += ctot[c]; }
        cbase[nbc] = acc;
    }
    __syncthreads();
    for (int c = t; c < nbc; c += 256) {
        const int cb = cbase[c];
        for (int b = 0; b < NBLK_SORT; b++) cnt[c * NBLK_SORT + b] += cb;
        chunkBase[c] = cb;
    }
    if (t == 0) chunkBase[nbc] = cbase[nbc];
}

__global__ __launch_bounds__(256) void bucket_scatter(
    const int* __restrict__ src, const int* __restrict__ dst,
    const int* __restrict__ cnt, int* __restrict__ temp, int E, int nbc)
{
    __shared__ int lcur[1024];
    const int tid = threadIdx.x, b = blockIdx.x;
    for (int c = tid; c < nbc; c += 256) lcur[c] = cnt[c * gridDim.x + b];
    __syncthreads();
    const int per = (E + gridDim.x - 1) / gridDim.x;
    const int e0 = b * per, e1 = min(E, e0 + per);
    for (int e = e0 + tid; e < e1; e += 256) {
        const int d = dst[e];
        const int pos = atomicAdd(&lcur[d >> 10], 1);
        temp[pos] = ((d & 1023) << 22) | src[e];
    }
}

__global__ __launch_bounds__(256) void chunk_place(
    const int* __restrict__ temp, const int* __restrict__ chunkBase,
    int* __restrict__ col, int* __restrict__ deg, int* __restrict__ rowptr,
    int N)
{
    __shared__ int lcnt[1024];
    __shared__ int lcur[1024];
    __shared__ int sh[256];
    const int tid = threadIdx.x, c = blockIdx.x;
    const int s = chunkBase[c], e2 = chunkBase[c + 1];

    for (int i = tid; i < 1024; i += 256) lcnt[i] = 0;
    __syncthreads();
    for (int i = s + tid; i < e2; i += 256)
        atomicAdd(&lcnt[((unsigned)temp[i]) >> 22], 1);
    __syncthreads();

    const int b4 = tid * 4;
    const int v0 = lcnt[b4], v1 = lcnt[b4 + 1], v2 = lcnt[b4 + 2], v3 = lcnt[b4 + 3];
    const int ts = v0 + v1 + v2 + v3;
    sh[tid] = ts;
    __syncthreads();
    for (int off = 1; off < 256; off <<= 1) {
        int x = (tid >= off) ? sh[tid - off] : 0;
        __syncthreads();
        sh[tid] += x;
        __syncthreads();
    }
    const int run = sh[tid] - ts;
    lcur[b4]     = s + run;
    lcur[b4 + 1] = s + run + v0;
    lcur[b4 + 2] = s + run + v0 + v1;
    lcur[b4 + 3] = s + run + v0 + v1 + v2;
    const int node0 = c << 10;
    if (node0 + b4 < N)     { deg[node0 + b4]     = v0; rowptr[node0 + b4]     = lcur[b4]; }
    if (node0 + b4 + 1 < N) { deg[node0 + b4 + 1] = v1; rowptr[node0 + b4 + 1] = lcur[b4 + 1]; }
    if (node0 + b4 + 2 < N) { deg[node0 + b4 + 2] = v2; rowptr[node0 + b4 + 2] = lcur[b4 + 2]; }
    if (node0 + b4 + 3 < N) { deg[node0 + b4 + 3] = v3; rowptr[node0 + b4 + 3] = lcur[b4 + 3]; }
    __syncthreads();

    for (int i = s + tid; i < e2; i += 256) {
        const unsigned p = (unsigned)temp[i];
        const int pos = atomicAdd(&lcur[p >> 22], 1);
        col[pos] = (int)(p & 0x3FFFFFu);
    }
}

// ---------------------------------------------------------------------------
// MFMA GEMM, bf16 in / bf16 out. outb[N,128] = act(bn(stage(in)) @ W + bias).
// A staged as single bf16 (one RNE round); W is bf16 hi+lo (2 MFMA).
// flags: 1=BN apply+relu on staged input, 2=relu on output,
//        4=emit BN stats partials, 32=gather-aggregate during staging,
//        64=input is bf16 (AinB), else fp32 (Ain32 -- lin layer only).
// Block 256 thr = 4 waves, tile 64x128; wave w -> cols w*32..+31 (acc[4][2]).
// LDS 17408 B -> 8 blocks/CU residency.
// ---------------------------------------------------------------------------
__global__ __launch_bounds__(256) void gemm_mfma(
    const float* __restrict__ Ain32, const unsigned short* __restrict__ AinB,
    const int* __restrict__ rowptr, const int* __restrict__ deg,
    const int* __restrict__ col,
    const unsigned short* __restrict__ Wh, const unsigned short* __restrict__ Wl,
    const float* __restrict__ bias, const float* __restrict__ ss,
    unsigned short* __restrict__ outb, float* __restrict__ part,
    int N, int flags)
{
    __shared__ __align__(16) unsigned short As[64][136];
    const int tid = threadIdx.x;
    const int row0 = blockIdx.x * 64;

    if (flags & 32) {
        // ---- staging with fused aggregation: 16 groups x 16 lanes ----
        const int g = tid >> 4;
        const int l = tid & 15;
        #pragma unroll
        for (int rr = 0; rr < 4; rr++) {
            const int r = g + rr * 16;
            const int row = row0 + r;
            float4 a0 = make_float4(0.f, 0.f, 0.f, 0.f);
            float4 a1 = make_float4(0.f, 0.f, 0.f, 0.f);
            if (row < N) {
                const uint4 su = *(const uint4*)(AinB + (size_t)row * 128 + l * 8);
                a0.x = bfu_lo(su.x); a0.y = bfu_hi(su.x);
                a0.z = bfu_lo(su.y); a0.w = bfu_hi(su.y);
                a1.x = bfu_lo(su.z); a1.y = bfu_hi(su.z);
                a1.z = bfu_lo(su.w); a1.w = bfu_hi(su.w);
                const int start = rowptr[row];
                const int cnt = deg[row];
                int j = 0;
                for (; j + 1 < cnt; j += 2) {
                    const int c0i = col[start + j];
                    const int c1i = col[start + j + 1];
                    const uint4 u0 = *(const uint4*)(AinB + (size_t)c0i * 128 + l * 8);
                    const uint4 u1 = *(const uint4*)(AinB + (size_t)c1i * 128 + l * 8);
                    a0.x += bfu_lo(u0.x); a0.y += bfu_hi(u0.x);
                    a0.z += bfu_lo(u0.y); a0.w += bfu_hi(u0.y);
                    a1.x += bfu_lo(u0.z); a1.y += bfu_hi(u0.z);
                    a1.z += bfu_lo(u0.w); a1.w += bfu_hi(u0.w);
                    a0.x += bfu_lo(u1.x); a0.y += bfu_hi(u1.x);
                    a0.z += bfu_lo(u1.y); a0.w += bfu_hi(u1.y);
                    a1.x += bfu_lo(u1.z); a1.y += bfu_hi(u1.z);
                    a1.z += bfu_lo(u1.w); a1.w += bfu_hi(u1.w);
                }
                if (j < cnt) {
                    const int c0i = col[start + j];
                    const uint4 u0 = *(const uint4*)(AinB + (size_t)c0i * 128 + l * 8);
                    a0.x += bfu_lo(u0.x); a0.y += bfu_hi(u0.x);
                    a0.z += bfu_lo(u0.y); a0.w += bfu_hi(u0.y);
                    a1.x += bfu_lo(u0.z); a1.y += bfu_hi(u0.z);
                    a1.z += bfu_lo(u0.w); a1.w += bfu_hi(u0.w);
                }
            }
            uint4 uh;
            uh.x = pkbf(a0.x, a0.y);
            uh.y = pkbf(a0.z, a0.w);
            uh.z = pkbf(a1.x, a1.y);
            uh.w = pkbf(a1.z, a1.w);
            *(uint4*)&As[r][l * 8] = uh;
        }
    } else if (flags & 64) {
        // ---- bf16 staging (optional BN apply + relu): 64 rows x 16 groups ----
        for (int i = tid; i < 64 * 16; i += 256) {
            const int r = i >> 4, c8 = i & 15;
            const int row = row0 + r;
            if (row < N) {
                uint4 u = *(const uint4*)(AinB + (size_t)row * 128 + c8 * 8);
                if (flags & 1) {
                    float4 v0, v1;
                    v0.x = bfu_lo(u.x); v0.y = bfu_hi(u.x);
                    v0.z = bfu_lo(u.y); v0.w = bfu_hi(u.y);
                    v1.x = bfu_lo(u.z); v1.y = bfu_hi(u.z);
                    v1.z = bfu_lo(u.w); v1.w = bfu_hi(u.w);
                    const float4 sc0 = ((const float4*)ss)[c8 * 2];
                    const float4 sc1 = ((const float4*)ss)[c8 * 2 + 1];
                    const float4 sh0 = ((const float4*)(ss + 128))[c8 * 2];
                    const float4 sh1 = ((const float4*)(ss + 128))[c8 * 2 + 1];
                    v0.x = fmaxf(v0.x * sc0.x + sh0.x, 0.f);
                    v0.y = fmaxf(v0.y * sc0.y + sh0.y, 0.f);
                    v0.z = fmaxf(v0.z * sc0.z + sh0.z, 0.f);
                    v0.w = fmaxf(v0.w * sc0.w + sh0.w, 0.f);
                    v1.x = fmaxf(v1.x * sc1.x + sh1.x, 0.f);
                    v1.y = fmaxf(v1.y * sc1.y + sh1.y, 0.f);
                    v1.z = fmaxf(v1.z * sc1.z + sh1.z, 0.f);
                    v1.w = fmaxf(v1.w * sc1.w + sh1.w, 0.f);
                    u.x = pkbf(v0.x, v0.y);
                    u.y = pkbf(v0.z, v0.w);
                    u.z = pkbf(v1.x, v1.y);
                    u.w = pkbf(v1.z, v1.w);
                }
                *(uint4*)&As[r][c8 * 8] = u;
            } else {
                *(uint4*)&As[r][c8 * 8] = make_uint4(0, 0, 0, 0);
            }
        }
    } else {
        // ---- fp32 staging (lin layer: x input) ----
        for (int i = tid; i < 64 * 32; i += 256) {
            const int r = i >> 5, c4 = i & 31;
            const int row = row0 + r;
            float4 v = make_float4(0.f, 0.f, 0.f, 0.f);
            if (row < N) v = ((const float4*)(Ain32 + (size_t)row * 128))[c4];
            uint2 uh;
            uh.x = pkbf(v.x, v.y);
            uh.y = pkbf(v.z, v.w);
            *(uint2*)&As[r][c4 * 4] = uh;
        }
    }
    __syncthreads();

    const int w    = tid >> 6;
    const int lane = tid & 63;
    const int ln   = lane & 15;
    const int lq   = lane >> 4;
    const int c0   = w * 32;

    float4v acc[4][2];
    #pragma unroll
    for (int nt = 0; nt < 2; nt++) {
        const float bv = bias[c0 + nt * 16 + ln];
        #pragma unroll
        for (int mt = 0; mt < 4; mt++) acc[mt][nt] = (float4v){bv, bv, bv, bv};
    }

    #pragma unroll
    for (int kc = 0; kc < 4; kc++) {
        const size_t b0 = (size_t)(c0 + ln) * 128 + kc * 32 + lq * 8;
        const size_t b1 = (size_t)(c0 + 16 + ln) * 128 + kc * 32 + lq * 8;
        const short8v bh0 = *(const short8v*)&Wh[b0];
        const short8v bl0 = *(const short8v*)&Wl[b0];
        const short8v bh1 = *(const short8v*)&Wh[b1];
        const short8v bl1 = *(const short8v*)&Wl[b1];
        #pragma unroll
        for (int mt = 0; mt < 4; mt++) {
            const short8v ah = *(const short8v*)&As[mt * 16 + ln][kc * 32 + lq * 8];
            acc[mt][0] = __builtin_amdgcn_mfma_f32_16x16x32_bf16(ah, bh0, acc[mt][0], 0, 0, 0);
            acc[mt][0] = __builtin_amdgcn_mfma_f32_16x16x32_bf16(ah, bl0, acc[mt][0], 0, 0, 0);
            acc[mt][1] = __builtin_amdgcn_mfma_f32_16x16x32_bf16(ah, bh1, acc[mt][1], 0, 0, 0);
            acc[mt][1] = __builtin_amdgcn_mfma_f32_16x16x32_bf16(ah, bl1, acc[mt][1], 0, 0, 0);
        }
    }

    // ---- store bf16 (C/D: col=lane&15, row=quad*4+reg) ----
    #pragma unroll
    for (int mt = 0; mt < 4; mt++) {
        #pragma unroll
        for (int nt = 0; nt < 2; nt++) {
            const int colv = c0 + nt * 16 + ln;
            #pragma unroll
            for (int i = 0; i < 4; i++) {
                const int row = row0 + mt * 16 + lq * 4 + i;
                if (row < N) {
                    float v = acc[mt][nt][i];
                    if (flags & 2) v = fmaxf(v, 0.f);
                    outb[(size_t)row * 128 + colv] = f2bf(v);
                }
            }
        }
    }

    // ---- BN stats partials (pre-activation z); wave owns its 32 cols ----
    if (flags & 4) {
        #pragma unroll
        for (int nt = 0; nt < 2; nt++) {
            float s = 0.f, q = 0.f;
            #pragma unroll
            for (int mt = 0; mt < 4; mt++) {
                #pragma unroll
                for (int i = 0; i < 4; i++) {
                    const int row = row0 + mt * 16 + lq * 4 + i;
                    if (row < N) { const float v = acc[mt][nt][i]; s += v; q += v * v; }
                }
            }
            s += __shfl_xor(s, 16); s += __shfl_xor(s, 32);
            q += __shfl_xor(q, 16); q += __shfl_xor(q, 32);
            if (lq == 0) {
                const int colv = c0 + nt * 16 + ln;
                part[(size_t)colv * gridDim.x + blockIdx.x] = s;
                part[(size_t)(128 + colv) * gridDim.x + blockIdx.x] = q;
            }
        }
    }
}

// ---------------------------------------------------------------------------
// BN finalize: reduce partials -> scale[c], shift[c]. grid=128 (1/channel).
// ---------------------------------------------------------------------------
__global__ __launch_bounds__(256) void bn_finalize(
    const float* __restrict__ part, int nblk, float invN,
    const float* __restrict__ gamma, const float* __restrict__ beta,
    float* __restrict__ ss)
{
    __shared__ float shs[256], shq[256];
    const int c = blockIdx.x, t = threadIdx.x;
    float s = 0.f, q = 0.f;
    for (int b = t; b < nblk; b += 256) {
        s += part[(size_t)c * nblk + b];
        q += part[(size_t)(128 + c) * nblk + b];
    }
    shs[t] = s; shq[t] = q;
    __syncthreads();
    for (int o = 128; o > 0; o >>= 1) {
        if (t < o) { shs[t] += shs[t + o]; shq[t] += shq[t + o]; }
        __syncthreads();
    }
    if (t == 0) {
        const float mu = shs[0] * invN;
        const float var = shq[0] * invN - mu * mu;
        const float sc = rsqrtf(fmaxf(var, 0.f) + 1e-5f) * gamma[c];
        ss[c] = sc;
        ss[128 + c] = beta[c] - mu * sc;
    }
}

// ---------------------------------------------------------------------------
// Classifier: out[e] = dot(hb[ia[e]], hb[ib[e]]), bf16 reads, fp32 math.
// ---------------------------------------------------------------------------
__global__ __launch_bounds__(256) void edge_dot(
    const unsigned short* __restrict__ hb, const int* __restrict__ ia,
    const int* __restrict__ ib, float* __restrict__ out, int EL)
{
    const int stride = gridDim.x * blockDim.x;
    const long long total = (long long)EL * 16;
    for (long long i = (long long)blockIdx.x * blockDim.x + threadIdx.x; i < total; i += stride) {
        const int e = (int)(i >> 4);
        const int l = (int)(i & 15);
        const int a = ia[e];
        const int b = ib[e];
        const uint4 u = *(const uint4*)(hb + (size_t)a * 128 + l * 8);
        const uint4 v = *(const uint4*)(hb + (size_t)b * 128 + l * 8);
        float d = bfu_lo(u.x) * bfu_lo(v.x) + bfu_hi(u.x) * bfu_hi(v.x)
                + bfu_lo(u.y) * bfu_lo(v.y) + bfu_hi(u.y) * bfu_hi(v.y)
                + bfu_lo(u.z) * bfu_lo(v.z) + bfu_hi(u.z) * bfu_hi(v.z)
                + bfu_lo(u.w) * bfu_lo(v.w) + bfu_hi(u.w) * bfu_hi(v.w);
        d += __shfl_xor(d, 1); d += __shfl_xor(d, 2);
        d += __shfl_xor(d, 4); d += __shfl_xor(d, 8);
        if (l == 0) out[e] = d;
    }
}

extern "C" void kernel_launch(void* const* d_in, const int* in_sizes, int n_in,
                              void* d_out, int out_size, void* d_ws, size_t ws_size,
                              hipStream_t stream)
{
    const float* x     = (const float*)d_in[0];
    const float* lin_w = (const float*)d_in[1];
    const float* lin_b = (const float*)d_in[2];
    const float* W1    = (const float*)d_in[3];
    const float* b1    = (const float*)d_in[4];
    const float* gamma = (const float*)d_in[5];
    const float* beta  = (const float*)d_in[6];
    const float* W2    = (const float*)d_in[7];
    const float* b2    = (const float*)d_in[8];
    const int*   ei    = (const int*)d_in[9];
    const int*   eli   = (const int*)d_in[10];
    float* out = (float*)d_out;

    const int N  = in_sizes[0] / 128;
    const int E  = in_sizes[9] / 2;
    const int EL = in_sizes[10] / 2;
    const size_t nd = (size_t)N * 128;
    const int nbc = (N + 1023) >> 10;            // 1024-node chunks
    const int gemm_grid = (N + 63) / 64;

    // ws: hbH | hbZ | deg | rowptr | cnt | chunkBase | temp | col | wts | part | ss
    unsigned short* hbH = (unsigned short*)d_ws;
    unsigned short* hbZ = hbH + nd;
    int*   deg    = (int*)(hbZ + nd);
    int*   rowptr = deg + N;
    int*   cnt    = rowptr + N;                  // [nbc][NBLK_SORT]
    int*   chunkBase = cnt + (size_t)nbc * NBLK_SORT;
    int*   temp   = chunkBase + nbc + 1;
    int*   col    = temp + E;
    unsigned short* wt_hi = (unsigned short*)(col + E);
    unsigned short* wt_lo = wt_hi + 7 * 16384;
    float* part   = (float*)(wt_lo + 7 * 16384);
    float* ss     = part + (size_t)256 * gemm_grid;

    const float invN = 1.0f / (float)N;

    // ---- weight prep + bucketed CSR build ----
    prep_w<<<448, 256, 0, stream>>>(lin_w, W1, W2, wt_hi, wt_lo);
    chunk_count<<<NBLK_SORT, 256, 0, stream>>>(ei + E, cnt, E, nbc);
    chunk_scan<<<1, 256, 0, stream>>>(cnt, chunkBase, nbc);
    bucket_scatter<<<NBLK_SORT, 256, 0, stream>>>(ei, ei + E, cnt, temp, E, nbc);
    chunk_place<<<nbc, 256, 0, stream>>>(temp, chunkBase, col, deg, rowptr, N);

    // ---- h = x @ lin_w + lin_b  -> hbH (bf16) ----
    gemm_mfma<<<gemm_grid, 256, 0, stream>>>(x, nullptr, nullptr, nullptr, nullptr,
                                             wt_hi, wt_lo, lin_b, ss, hbH, part, N, 0);

    for (int l = 0; l < 3; l++) {
        const unsigned short* w1h = wt_hi + (size_t)(1 + l) * 16384;
        const unsigned short* w1l = wt_lo + (size_t)(1 + l) * 16384;
        const unsigned short* w2h = wt_hi + (size_t)(4 + l) * 16384;
        const unsigned short* w2l = wt_lo + (size_t)(4 + l) * 16384;
        // z = (h + agg) @ W1 + b1 : gather from hbH, write hbZ, BN partials
        gemm_mfma<<<gemm_grid, 256, 0, stream>>>(nullptr, hbH, rowptr, deg, col,
                                                 w1h, w1l, b1 + (size_t)l * 128,
                                                 ss, hbZ, part, N, 4 | 32 | 64);
        bn_finalize<<<128, 256, 0, stream>>>(part, gemm_grid, invN,
                                             gamma + (size_t)l * 128,
                                             beta + (size_t)l * 128, ss);
        // h = relu(bn(z) @ W2 + b2) : stage hbZ + BN + relu, write hbH
        gemm_mfma<<<gemm_grid, 256, 0, stream>>>(nullptr, hbZ, nullptr, nullptr, nullptr,
                                                 w2h, w2l, b2 + (size_t)l * 128,
                                                 ss, hbH, part, N, 1 | 2 | 64);
    }

    edge_dot<<<8192, 256, 0, stream>>>(hbH, eli, eli + EL, out, EL);
}

// Round 9
// 550.279 us; speedup vs baseline: 15.9617x; 1.1409x over previous
//
#include <hip/hip_runtime.h>
#include <hip/hip_bf16.h>

// ===========================================================================
// GIN link-pred. R8->R9:
//  - chunk_scan (1-block serial, ~45 us on one CU) -> parallel scan_blocks
//    (98 blk x 512 thr) + tiny scan_ctot; chunk base folded into
//    bucket_scatter's cursor init.
//  - lin/gemm2 -> gemm_stream with 128-row tiles (half the blocks, half the
//    W L2 traffic, amortized staging/epilogue).
//  - gather staging unroll x4 (deeper MLP on the random 256B row reads).
// R8 evidence: gather pinned at ~99 us / 187 MB FETCH across 3 structural
// variants => near random-gather floor; remaining time is scan + streaming
// GEMMs + edge_dot.
// Requires N < 2^22. CSR via chunk-bucketed counting sort.
// ===========================================================================

typedef __attribute__((ext_vector_type(8))) short short8v;
typedef __attribute__((ext_vector_type(4))) float float4v;

#define NBLK_SORT 512

__device__ __forceinline__ unsigned short f2bf(float f) {
    union { float f; unsigned u; } v; v.f = f;
    unsigned u = v.u;
    unsigned r = u + 0x7fffu + ((u >> 16) & 1u);   // RNE
    return (unsigned short)(r >> 16);
}
__device__ __forceinline__ float bf2f(unsigned short h) {
    union { unsigned u; float f; } v; v.u = ((unsigned)h) << 16;
    return v.f;
}
__device__ __forceinline__ float bfu_lo(unsigned u) {
    union { unsigned v; float f; } x; x.v = u << 16; return x.f;
}
__device__ __forceinline__ float bfu_hi(unsigned u) {
    union { unsigned v; float f; } x; x.v = u & 0xffff0000u; return x.f;
}
__device__ __forceinline__ unsigned pkbf(float x, float y) {
    __hip_bfloat162 t = __float22bfloat162_rn(float2{x, y});
    union { __hip_bfloat162 b; unsigned u; } c; c.b = t;
    return c.u;
}

// ---------------------------------------------------------------------------
// Weight prep: 7 128x128 fp32 -> transposed (n-major) bf16 hi/lo splits.
// ---------------------------------------------------------------------------
__global__ __launch_bounds__(256) void prep_w(
    const float* __restrict__ lin_w, const float* __restrict__ W1,
    const float* __restrict__ W2,
    unsigned short* __restrict__ wt_hi, unsigned short* __restrict__ wt_lo)
{
    int idx = blockIdx.x * 256 + threadIdx.x;
    if (idx >= 7 * 16384) return;
    int m = idx >> 14;
    int r = idx & 16383;          // r = k*128 + n
    int k = r >> 7, n = r & 127;
    const float* src = (m == 0) ? lin_w
                     : (m <= 3) ? W1 + (size_t)(m - 1) * 16384
                                : W2 + (size_t)(m - 4) * 16384;
    float w = src[r];
    unsigned short hi = f2bf(w);
    unsigned short lo = f2bf(w - bf2f(hi));
    wt_hi[(size_t)m * 16384 + n * 128 + k] = hi;   // [n][k]
    wt_lo[(size_t)m * 16384 + n * 128 + k] = lo;
}

// ---------------------------------------------------------------------------
// Bucketed counting sort -> CSR (chunk = 1024 dst nodes).
// ---------------------------------------------------------------------------
__global__ __launch_bounds__(256) void chunk_count(
    const int* __restrict__ dst, int* __restrict__ cnt, int E, int nbc)
{
    __shared__ int l[1024];
    const int tid = threadIdx.x, b = blockIdx.x;
    for (int i = tid; i < nbc; i += 256) l[i] = 0;
    __syncthreads();
    const int per = (E + gridDim.x - 1) / gridDim.x;
    const int e0 = b * per, e1 = min(E, e0 + per);
    for (int e = e0 + tid; e < e1; e += 256)
        atomicAdd(&l[dst[e] >> 10], 1);
    __syncthreads();
    for (int c = tid; c < nbc; c += 256) cnt[c * gridDim.x + b] = l[c];
}

// Per-chunk parallel exclusive scan of cnt[c][0..511]; total -> ctot[c].
__global__ __launch_bounds__(512) void scan_blocks(
    int* __restrict__ cnt, int* __restrict__ ctot)
{
    __shared__ int sh[512];
    const int c = blockIdx.x, t = threadIdx.x;
    const int v = cnt[c * NBLK_SORT + t];
    sh[t] = v;
    __syncthreads();
    for (int off = 1; off < 512; off <<= 1) {
        int x = (t >= off) ? sh[t - off] : 0;
        __syncthreads();
        sh[t] += x;
        __syncthreads();
    }
    cnt[c * NBLK_SORT + t] = sh[t] - v;   // exclusive
    if (t == 511) ctot[c] = sh[511];
}

// Serial scan of ~98 chunk totals -> chunkBase[0..nbc].
__global__ void scan_ctot(const int* __restrict__ ctot,
                          int* __restrict__ chunkBase, int nbc)
{
    if (threadIdx.x == 0 && blockIdx.x == 0) {
        int acc = 0;
        for (int c = 0; c < nbc; c++) { chunkBase[c] = acc; acc += ctot[c]; }
        chunkBase[nbc] = acc;
    }
}

__global__ __launch_bounds__(256) void bucket_scatter(
    const int* __restrict__ src, const int* __restrict__ dst,
    const int* __restrict__ cnt, const int* __restrict__ chunkBase,
    int* __restrict__ temp, int E, int nbc)
{
    __shared__ int lcur[1024];
    const int tid = threadIdx.x, b = blockIdx.x;
    for (int c = tid; c < nbc; c += 256)
        lcur[c] = cnt[c * gridDim.x + b] + chunkBase[c];
    __syncthreads();
    const int per = (E + gridDim.x - 1) / gridDim.x;
    const int e0 = b * per, e1 = min(E, e0 + per);
    for (int e = e0 + tid; e < e1; e += 256) {
        const int d = dst[e];
        const int pos = atomicAdd(&lcur[d >> 10], 1);
        temp[pos] = ((d & 1023) << 22) | src[e];
    }
}

__global__ __launch_bounds__(256) void chunk_place(
    const int* __restrict__ temp, const int* __restrict__ chunkBase,
    int* __restrict__ col, int* __restrict__ deg, int* __restrict__ rowptr,
    int N)
{
    __shared__ int lcnt[1024];
    __shared__ int lcur[1024];
    __shared__ int sh[256];
    const int tid = threadIdx.x, c = blockIdx.x;
    const int s = chunkBase[c], e2 = chunkBase[c + 1];

    for (int i = tid; i < 1024; i += 256) lcnt[i] = 0;
    __syncthreads();
    for (int i = s + tid; i < e2; i += 256)
        atomicAdd(&lcnt[((unsigned)temp[i]) >> 22], 1);
    __syncthreads();

    const int b4 = tid * 4;
    const int v0 = lcnt[b4], v1 = lcnt[b4 + 1], v2 = lcnt[b4 + 2], v3 = lcnt[b4 + 3];
    const int ts = v0 + v1 + v2 + v3;
    sh[tid] = ts;
    __syncthreads();
    for (int off = 1; off < 256; off <<= 1) {
        int x = (tid >= off) ? sh[tid - off] : 0;
        __syncthreads();
        sh[tid] += x;
        __syncthreads();
    }
    const int run = sh[tid] - ts;
    lcur[b4]     = s + run;
    lcur[b4 + 1] = s + run + v0;
    lcur[b4 + 2] = s + run + v0 + v1;
    lcur[b4 + 3] = s + run + v0 + v1 + v2;
    const int node0 = c << 10;
    if (node0 + b4 < N)     { deg[node0 + b4]     = v0; rowptr[node0 + b4]     = lcur[b4]; }
    if (node0 + b4 + 1 < N) { deg[node0 + b4 + 1] = v1; rowptr[node0 + b4 + 1] = lcur[b4 + 1]; }
    if (node0 + b4 + 2 < N) { deg[node0 + b4 + 2] = v2; rowptr[node0 + b4 + 2] = lcur[b4 + 2]; }
    if (node0 + b4 + 3 < N) { deg[node0 + b4 + 3] = v3; rowptr[node0 + b4 + 3] = lcur[b4 + 3]; }
    __syncthreads();

    for (int i = s + tid; i < e2; i += 256) {
        const unsigned p = (unsigned)temp[i];
        const int pos = atomicAdd(&lcur[p >> 22], 1);
        col[pos] = (int)(p & 0x3FFFFFu);
    }
}

// ---------------------------------------------------------------------------
// Gather-GEMM (gemm1): hbZ[N,128] = (h + sum_j h[col]) @ W + b, BN partials.
// 64-row tile (more blocks = more latticework for gather latency hiding).
// A staged single-bf16; W hi+lo (2 MFMA). Neighbor loop unrolled x4.
// ---------------------------------------------------------------------------
__global__ __launch_bounds__(256) void gemm_gather(
    const unsigned short* __restrict__ AinB,
    const int* __restrict__ rowptr, const int* __restrict__ deg,
    const int* __restrict__ col,
    const unsigned short* __restrict__ Wh, const unsigned short* __restrict__ Wl,
    const float* __restrict__ bias,
    unsigned short* __restrict__ outb, float* __restrict__ part, int N)
{
    __shared__ __align__(16) unsigned short As[64][136];
    const int tid = threadIdx.x;
    const int row0 = blockIdx.x * 64;

    const int g = tid >> 4;
    const int l = tid & 15;
    #pragma unroll
    for (int rr = 0; rr < 4; rr++) {
        const int r = g + rr * 16;
        const int row = row0 + r;
        float4 a0 = make_float4(0.f, 0.f, 0.f, 0.f);
        float4 a1 = make_float4(0.f, 0.f, 0.f, 0.f);
        if (row < N) {
            const uint4 su = *(const uint4*)(AinB + (size_t)row * 128 + l * 8);
            a0.x = bfu_lo(su.x); a0.y = bfu_hi(su.x);
            a0.z = bfu_lo(su.y); a0.w = bfu_hi(su.y);
            a1.x = bfu_lo(su.z); a1.y = bfu_hi(su.z);
            a1.z = bfu_lo(su.w); a1.w = bfu_hi(su.w);
            const int start = rowptr[row];
            const int cnt = deg[row];
            int j = 0;
            for (; j + 3 < cnt; j += 4) {
                const int c0i = col[start + j];
                const int c1i = col[start + j + 1];
                const int c2i = col[start + j + 2];
                const int c3i = col[start + j + 3];
                const uint4 u0 = *(const uint4*)(AinB + (size_t)c0i * 128 + l * 8);
                const uint4 u1 = *(const uint4*)(AinB + (size_t)c1i * 128 + l * 8);
                const uint4 u2 = *(const uint4*)(AinB + (size_t)c2i * 128 + l * 8);
                const uint4 u3 = *(const uint4*)(AinB + (size_t)c3i * 128 + l * 8);
                a0.x += bfu_lo(u0.x); a0.y += bfu_hi(u0.x);
                a0.z += bfu_lo(u0.y); a0.w += bfu_hi(u0.y);
                a1.x += bfu_lo(u0.z); a1.y += bfu_hi(u0.z);
                a1.z += bfu_lo(u0.w); a1.w += bfu_hi(u0.w);
                a0.x += bfu_lo(u1.x); a0.y += bfu_hi(u1.x);
                a0.z += bfu_lo(u1.y); a0.w += bfu_hi(u1.y);
                a1.x += bfu_lo(u1.z); a1.y += bfu_hi(u1.z);
                a1.z += bfu_lo(u1.w); a1.w += bfu_hi(u1.w);
                a0.x += bfu_lo(u2.x); a0.y += bfu_hi(u2.x);
                a0.z += bfu_lo(u2.y); a0.w += bfu_hi(u2.y);
                a1.x += bfu_lo(u2.z); a1.y += bfu_hi(u2.z);
                a1.z += bfu_lo(u2.w); a1.w += bfu_hi(u2.w);
                a0.x += bfu_lo(u3.x); a0.y += bfu_hi(u3.x);
                a0.z += bfu_lo(u3.y); a0.w += bfu_hi(u3.y);
                a1.x += bfu_lo(u3.z); a1.y += bfu_hi(u3.z);
                a1.z += bfu_lo(u3.w); a1.w += bfu_hi(u3.w);
            }
            for (; j < cnt; j++) {
                const int c0i = col[start + j];
                const uint4 u0 = *(const uint4*)(AinB + (size_t)c0i * 128 + l * 8);
                a0.x += bfu_lo(u0.x); a0.y += bfu_hi(u0.x);
                a0.z += bfu_lo(u0.y); a0.w += bfu_hi(u0.y);
                a1.x += bfu_lo(u0.z); a1.y += bfu_hi(u0.z);
                a1.z += bfu_lo(u0.w); a1.w += bfu_hi(u0.w);
            }
        }
        uint4 uh;
        uh.x = pkbf(a0.x, a0.y);
        uh.y = pkbf(a0.z, a0.w);
        uh.z = pkbf(a1.x, a1.y);
        uh.w = pkbf(a1.z, a1.w);
        *(uint4*)&As[r][l * 8] = uh;
    }
    __syncthreads();

    const int w    = tid >> 6;
    const int lane = tid & 63;
    const int ln   = lane & 15;
    const int lq   = lane >> 4;
    const int c0   = w * 32;

    float4v acc[4][2];
    #pragma unroll
    for (int nt = 0; nt < 2; nt++) {
        const float bv = bias[c0 + nt * 16 + ln];
        #pragma unroll
        for (int mt = 0; mt < 4; mt++) acc[mt][nt] = (float4v){bv, bv, bv, bv};
    }

    #pragma unroll
    for (int kc = 0; kc < 4; kc++) {
        const size_t b0 = (size_t)(c0 + ln) * 128 + kc * 32 + lq * 8;
        const size_t b1 = (size_t)(c0 + 16 + ln) * 128 + kc * 32 + lq * 8;
        const short8v bh0 = *(const short8v*)&Wh[b0];
        const short8v bl0 = *(const short8v*)&Wl[b0];
        const short8v bh1 = *(const short8v*)&Wh[b1];
        const short8v bl1 = *(const short8v*)&Wl[b1];
        #pragma unroll
        for (int mt = 0; mt < 4; mt++) {
            const short8v ah = *(const short8v*)&As[mt * 16 + ln][kc * 32 + lq * 8];
            acc[mt][0] = __builtin_amdgcn_mfma_f32_16x16x32_bf16(ah, bh0, acc[mt][0], 0, 0, 0);
            acc[mt][0] = __builtin_amdgcn_mfma_f32_16x16x32_bf16(ah, bl0, acc[mt][0], 0, 0, 0);
            acc[mt][1] = __builtin_amdgcn_mfma_f32_16x16x32_bf16(ah, bh1, acc[mt][1], 0, 0, 0);
            acc[mt][1] = __builtin_amdgcn_mfma_f32_16x16x32_bf16(ah, bl1, acc[mt][1], 0, 0, 0);
        }
    }

    #pragma unroll
    for (int mt = 0; mt < 4; mt++) {
        #pragma unroll
        for (int nt = 0; nt < 2; nt++) {
            const int colv = c0 + nt * 16 + ln;
            #pragma unroll
            for (int i = 0; i < 4; i++) {
                const int row = row0 + mt * 16 + lq * 4 + i;
                if (row < N)
                    outb[(size_t)row * 128 + colv] = f2bf(acc[mt][nt][i]);
            }
        }
    }

    // BN stats partials (pre-activation z); wave owns its 32 cols
    #pragma unroll
    for (int nt = 0; nt < 2; nt++) {
        float s = 0.f, q = 0.f;
        #pragma unroll
        for (int mt = 0; mt < 4; mt++) {
            #pragma unroll
            for (int i = 0; i < 4; i++) {
                const int row = row0 + mt * 16 + lq * 4 + i;
                if (row < N) { const float v = acc[mt][nt][i]; s += v; q += v * v; }
            }
        }
        s += __shfl_xor(s, 16); s += __shfl_xor(s, 32);
        q += __shfl_xor(q, 16); q += __shfl_xor(q, 32);
        if (lq == 0) {
            const int colv = c0 + nt * 16 + ln;
            part[(size_t)colv * gridDim.x + blockIdx.x] = s;
            part[(size_t)(128 + colv) * gridDim.x + blockIdx.x] = q;
        }
    }
}

// ---------------------------------------------------------------------------
// Streaming GEMM (lin, gemm2): 128-row tile, acc[8][2].
// flags: 1=BN apply+relu on staged input, 2=relu out, 64=bf16 input.
// ---------------------------------------------------------------------------
__global__ __launch_bounds__(256) void gemm_stream(
    const float* __restrict__ Ain32, const unsigned short* __restrict__ AinB,
    const unsigned short* __restrict__ Wh, const unsigned short* __restrict__ Wl,
    const float* __restrict__ bias, const float* __restrict__ ss,
    unsigned short* __restrict__ outb, int N, int flags)
{
    __shared__ __align__(16) unsigned short As[128][136];
    const int tid = threadIdx.x;
    const int row0 = blockIdx.x * 128;

    if (flags & 64) {
        for (int i = tid; i < 128 * 16; i += 256) {
            const int r = i >> 4, c8 = i & 15;
            const int row = row0 + r;
            uint4 u = make_uint4(0, 0, 0, 0);
            if (row < N) {
                u = *(const uint4*)(AinB + (size_t)row * 128 + c8 * 8);
                if (flags & 1) {
                    float4 v0, v1;
                    v0.x = bfu_lo(u.x); v0.y = bfu_hi(u.x);
                    v0.z = bfu_lo(u.y); v0.w = bfu_hi(u.y);
                    v1.x = bfu_lo(u.z); v1.y = bfu_hi(u.z);
                    v1.z = bfu_lo(u.w); v1.w = bfu_hi(u.w);
                    const float4 sc0 = ((const float4*)ss)[c8 * 2];
                    const float4 sc1 = ((const float4*)ss)[c8 * 2 + 1];
                    const float4 sh0 = ((const float4*)(ss + 128))[c8 * 2];
                    const float4 sh1 = ((const float4*)(ss + 128))[c8 * 2 + 1];
                    v0.x = fmaxf(v0.x * sc0.x + sh0.x, 0.f);
                    v0.y = fmaxf(v0.y * sc0.y + sh0.y, 0.f);
                    v0.z = fmaxf(v0.z * sc0.z + sh0.z, 0.f);
                    v0.w = fmaxf(v0.w * sc0.w + sh0.w, 0.f);
                    v1.x = fmaxf(v1.x * sc1.x + sh1.x, 0.f);
                    v1.y = fmaxf(v1.y * sc1.y + sh1.y, 0.f);
                    v1.z = fmaxf(v1.z * sc1.z + sh1.z, 0.f);
                    v1.w = fmaxf(v1.w * sc1.w + sh1.w, 0.f);
                    u.x = pkbf(v0.x, v0.y);
                    u.y = pkbf(v0.z, v0.w);
                    u.z = pkbf(v1.x, v1.y);
                    u.w = pkbf(v1.z, v1.w);
                }
            }
            *(uint4*)&As[r][c8 * 8] = u;
        }
    } else {
        for (int i = tid; i < 128 * 32; i += 256) {
            const int r = i >> 5, c4 = i & 31;
            const int row = row0 + r;
            float4 v = make_float4(0.f, 0.f, 0.f, 0.f);
            if (row < N) v = ((const float4*)(Ain32 + (size_t)row * 128))[c4];
            uint2 uh;
            uh.x = pkbf(v.x, v.y);
            uh.y = pkbf(v.z, v.w);
            *(uint2*)&As[r][c4 * 4] = uh;
        }
    }
    __syncthreads();

    const int w    = tid >> 6;
    const int lane = tid & 63;
    const int ln   = lane & 15;
    const int lq   = lane >> 4;
    const int c0   = w * 32;

    float4v acc[8][2];
    #pragma unroll
    for (int nt = 0; nt < 2; nt++) {
        const float bv = bias[c0 + nt * 16 + ln];
        #pragma unroll
        for (int mt = 0; mt < 8; mt++) acc[mt][nt] = (float4v){bv, bv, bv, bv};
    }

    #pragma unroll
    for (int kc = 0; kc < 4; kc++) {
        const size_t b0 = (size_t)(c0 + ln) * 128 + kc * 32 + lq * 8;
        const size_t b1 = (size_t)(c0 + 16 + ln) * 128 + kc * 32 + lq * 8;
        const short8v bh0 = *(const short8v*)&Wh[b0];
        const short8v bl0 = *(const short8v*)&Wl[b0];
        const short8v bh1 = *(const short8v*)&Wh[b1];
        const short8v bl1 = *(const short8v*)&Wl[b1];
        #pragma unroll
        for (int mt = 0; mt < 8; mt++) {
            const short8v ah = *(const short8v*)&As[mt * 16 + ln][kc * 32 + lq * 8];
            acc[mt][0] = __builtin_amdgcn_mfma_f32_16x16x32_bf16(ah, bh0, acc[mt][0], 0, 0, 0);
            acc[mt][0] = __builtin_amdgcn_mfma_f32_16x16x32_bf16(ah, bl0, acc[mt][0], 0, 0, 0);
            acc[mt][1] = __builtin_amdgcn_mfma_f32_16x16x32_bf16(ah, bh1, acc[mt][1], 0, 0, 0);
            acc[mt][1] = __builtin_amdgcn_mfma_f32_16x16x32_bf16(ah, bl1, acc[mt][1], 0, 0, 0);
        }
    }

    #pragma unroll
    for (int mt = 0; mt < 8; mt++) {
        #pragma unroll
        for (int nt = 0; nt < 2; nt++) {
            const int colv = c0 + nt * 16 + ln;
            #pragma unroll
            for (int i = 0; i < 4; i++) {
                const int row = row0 + mt * 16 + lq * 4 + i;
                if (row < N) {
                    float v = acc[mt][nt][i];
                    if (flags & 2) v = fmaxf(v, 0.f);
                    outb[(size_t)row * 128 + colv] = f2bf(v);
                }
            }
        }
    }
}

// ---------------------------------------------------------------------------
// BN finalize: reduce partials -> scale[c], shift[c]. grid=128 (1/channel).
// ---------------------------------------------------------------------------
__global__ __launch_bounds__(256) void bn_finalize(
    const float* __restrict__ part, int nblk, float invN,
    const float* __restrict__ gamma, const float* __restrict__ beta,
    float* __restrict__ ss)
{
    __shared__ float shs[256], shq[256];
    const int c = blockIdx.x, t = threadIdx.x;
    float s = 0.f, q = 0.f;
    for (int b = t; b < nblk; b += 256) {
        s += part[(size_t)c * nblk + b];
        q += part[(size_t)(128 + c) * nblk + b];
    }
    shs[t] = s; shq[t] = q;
    __syncthreads();
    for (int o = 128; o > 0; o >>= 1) {
        if (t < o) { shs[t] += shs[t + o]; shq[t] += shq[t + o]; }
        __syncthreads();
    }
    if (t == 0) {
        const float mu = shs[0] * invN;
        const float var = shq[0] * invN - mu * mu;
        const float sc = rsqrtf(fmaxf(var, 0.f) + 1e-5f) * gamma[c];
        ss[c] = sc;
        ss[128 + c] = beta[c] - mu * sc;
    }
}

// ---------------------------------------------------------------------------
// Classifier: out[e] = dot(hb[ia[e]], hb[ib[e]]), bf16 reads, fp32 math.
// ---------------------------------------------------------------------------
__global__ __launch_bounds__(256) void edge_dot(
    const unsigned short* __restrict__ hb, const int* __restrict__ ia,
    const int* __restrict__ ib, float* __restrict__ out, int EL)
{
    const int stride = gridDim.x * blockDim.x;
    const long long total = (long long)EL * 16;
    for (long long i = (long long)blockIdx.x * blockDim.x + threadIdx.x; i < total; i += stride) {
        const int e = (int)(i >> 4);
        const int l = (int)(i & 15);
        const int a = ia[e];
        const int b = ib[e];
        const uint4 u = *(const uint4*)(hb + (size_t)a * 128 + l * 8);
        const uint4 v = *(const uint4*)(hb + (size_t)b * 128 + l * 8);
        float d = bfu_lo(u.x) * bfu_lo(v.x) + bfu_hi(u.x) * bfu_hi(v.x)
                + bfu_lo(u.y) * bfu_lo(v.y) + bfu_hi(u.y) * bfu_hi(v.y)
                + bfu_lo(u.z) * bfu_lo(v.z) + bfu_hi(u.z) * bfu_hi(v.z)
                + bfu_lo(u.w) * bfu_lo(v.w) + bfu_hi(u.w) * bfu_hi(v.w);
        d += __shfl_xor(d, 1); d += __shfl_xor(d, 2);
        d += __shfl_xor(d, 4); d += __shfl_xor(d, 8);
        if (l == 0) out[e] = d;
    }
}

extern "C" void kernel_launch(void* const* d_in, const int* in_sizes, int n_in,
                              void* d_out, int out_size, void* d_ws, size_t ws_size,
                              hipStream_t stream)
{
    const float* x     = (const float*)d_in[0];
    const float* lin_w = (const float*)d_in[1];
    const float* lin_b = (const float*)d_in[2];
    const float* W1    = (const float*)d_in[3];
    const float* b1    = (const float*)d_in[4];
    const float* gamma = (const float*)d_in[5];
    const float* beta  = (const float*)d_in[6];
    const float* W2    = (const float*)d_in[7];
    const float* b2    = (const float*)d_in[8];
    const int*   ei    = (const int*)d_in[9];
    const int*   eli   = (const int*)d_in[10];
    float* out = (float*)d_out;

    const int N  = in_sizes[0] / 128;
    const int E  = in_sizes[9] / 2;
    const int EL = in_sizes[10] / 2;
    const size_t nd = (size_t)N * 128;
    const int nbc = (N + 1023) >> 10;            // 1024-node chunks
    const int g_grid = (N + 63) / 64;            // gather-gemm grid
    const int s_grid = (N + 127) / 128;          // streaming-gemm grid

    // ws: hbH | hbZ | deg | rowptr | cnt | ctot | chunkBase | temp | col | wts | part | ss
    unsigned short* hbH = (unsigned short*)d_ws;
    unsigned short* hbZ = hbH + nd;
    int*   deg    = (int*)(hbZ + nd);
    int*   rowptr = deg + N;
    int*   cnt    = rowptr + N;                  // [nbc][NBLK_SORT]
    int*   ctot   = cnt + (size_t)nbc * NBLK_SORT;
    int*   chunkBase = ctot + nbc;
    int*   temp   = chunkBase + nbc + 1;
    int*   col    = temp + E;
    unsigned short* wt_hi = (unsigned short*)(col + E);
    unsigned short* wt_lo = wt_hi + 7 * 16384;
    float* part   = (float*)(wt_lo + 7 * 16384);
    float* ss     = part + (size_t)256 * g_grid;

    const float invN = 1.0f / (float)N;

    // ---- weight prep + bucketed CSR build ----
    prep_w<<<448, 256, 0, stream>>>(lin_w, W1, W2, wt_hi, wt_lo);
    chunk_count<<<NBLK_SORT, 256, 0, stream>>>(ei + E, cnt, E, nbc);
    scan_blocks<<<nbc, 512, 0, stream>>>(cnt, ctot);
    scan_ctot<<<1, 64, 0, stream>>>(ctot, chunkBase, nbc);
    bucket_scatter<<<NBLK_SORT, 256, 0, stream>>>(ei, ei + E, cnt, chunkBase, temp, E, nbc);
    chunk_place<<<nbc, 256, 0, stream>>>(temp, chunkBase, col, deg, rowptr, N);

    // ---- h = x @ lin_w + lin_b  -> hbH (bf16) ----
    gemm_stream<<<s_grid, 256, 0, stream>>>(x, nullptr, wt_hi, wt_lo, lin_b, ss,
                                            hbH, N, 0);

    for (int l = 0; l < 3; l++) {
        const unsigned short* w1h = wt_hi + (size_t)(1 + l) * 16384;
        const unsigned short* w1l = wt_lo + (size_t)(1 + l) * 16384;
        const unsigned short* w2h = wt_hi + (size_t)(4 + l) * 16384;
        const unsigned short* w2l = wt_lo + (size_t)(4 + l) * 16384;
        // z = (h + agg) @ W1 + b1 : gather from hbH, write hbZ, BN partials
        gemm_gather<<<g_grid, 256, 0, stream>>>(hbH, rowptr, deg, col,
                                                w1h, w1l, b1 + (size_t)l * 128,
                                                hbZ, part, N);
        bn_finalize<<<128, 256, 0, stream>>>(part, g_grid, invN,
                                             gamma + (size_t)l * 128,
                                             beta + (size_t)l * 128, ss);
        // h = relu(bn(z) @ W2 + b2) : stage hbZ + BN + relu, write hbH
        gemm_stream<<<s_grid, 256, 0, stream>>>(nullptr, hbZ, w2h, w2l,
                                                b2 + (size_t)l * 128, ss,
                                                hbH, N, 1 | 2 | 64);
    }

    edge_dot<<<8192, 256, 0, stream>>>(hbH, eli, eli + EL, out, EL);
}